// Round 1
// baseline (696.088 us; speedup 1.0000x reference)
//
#include <hip/hip_runtime.h>
#include <hip/hip_bf16.h>

#define B_SZ 8192
#define DIMS 1024
#define CLN 8
#define BM 128
#define PADMAX (B_SZ + CLN * BM)     // 9216
#define MAX_TILES (B_SZ / BM + CLN)  // 72

typedef __attribute__((ext_vector_type(8))) __bf16 bf16x8;
typedef __attribute__((ext_vector_type(8))) short short8;
typedef __attribute__((ext_vector_type(4))) float f32x4;

__device__ __forceinline__ short f2bf(float f) {
  __hip_bfloat16 h = __float2bfloat16(f);
  return __builtin_bit_cast(short, h);
}
__device__ __forceinline__ float bf2f(short s) {
  unsigned u = ((unsigned)(unsigned short)s) << 16;
  return __builtin_bit_cast(float, u);
}

__global__ void zero_kernel(int* counts) {
  if (threadIdx.x < CLN) counts[threadIdx.x] = 0;
}

// one wave per sample: sij = x . center[c], argmax (first max wins, like jnp.argmax)
__global__ void router_kernel(const float* __restrict__ x, const float* __restrict__ center,
                              int* __restrict__ router, int* __restrict__ counts) {
  const int s = blockIdx.x;
  const int lane = threadIdx.x;
  const float* xr = x + (size_t)s * DIMS;
  float p[CLN];
#pragma unroll
  for (int c = 0; c < CLN; ++c) p[c] = 0.f;
  for (int t = 0; t < DIMS / 64; ++t) {
    const int i = lane + t * 64;
    const float xv = xr[i];
#pragma unroll
    for (int c = 0; c < CLN; ++c) p[c] += xv * center[c * DIMS + i];
  }
#pragma unroll
  for (int c = 0; c < CLN; ++c) {
    for (int off = 32; off; off >>= 1) p[c] += __shfl_down(p[c], off);
  }
  if (lane == 0) {
    int best = 0; float bv = p[0];
#pragma unroll
    for (int c = 1; c < CLN; ++c) { if (p[c] > bv) { bv = p[c]; best = c; } }
    router[s] = best;
    atomicAdd(&counts[best], 1);
  }
}

// single thread: padded per-cluster ranges (multiple of BM) + tile table
__global__ void scan_kernel(const int* __restrict__ counts, int* padded_start, int* meta,
                            int* tile_c, int* tile_r, int* cursor) {
  if (threadIdx.x != 0 || blockIdx.x != 0) return;
  int ps = 0, nt = 0;
  for (int c = 0; c < CLN; ++c) {
    padded_start[c] = ps;
    cursor[c] = 0;
    const int t = (counts[c] + BM - 1) / BM;
    for (int i = 0; i < t; ++i) { tile_c[nt] = c; tile_r[nt] = ps + i * BM; ++nt; }
    ps += t * BM;
  }
  padded_start[CLN] = ps;
  meta[0] = nt;  // n_tiles
  meta[1] = ps;  // padded_total
}

__global__ void scatter_kernel(const int* __restrict__ router, const int* __restrict__ pstart,
                               int* __restrict__ cursor, int* __restrict__ order) {
  const int s = blockIdx.x * blockDim.x + threadIdx.x;
  if (s >= B_SZ) return;
  const int c = router[s];
  const int pos = pstart[c] + atomicAdd(&cursor[c], 1);
  order[pos] = s;
}

// fill padding slots with a duplicate valid sample of the same cluster
__global__ void fillpad_kernel(const int* __restrict__ counts, const int* __restrict__ pstart,
                               int* __restrict__ order) {
  const int p = blockIdx.x * blockDim.x + threadIdx.x;
  if (p >= PADMAX) return;
#pragma unroll
  for (int c = 0; c < CLN; ++c) {
    if (p >= pstart[c] && p < pstart[c + 1]) {
      const int idx = p - pstart[c];
      if (idx >= counts[c]) order[p] = order[pstart[c]];
      break;
    }
  }
}

// 128x128 tile, 4 waves (2x2 of 64x64), mfma_f32_16x16x32_bf16.
// A: activations (layer0 gathers fp32 x via order[]), B: w0[k][n]*wc[c][k][n] gated on the fly,
// stored transposed in LDS (Bs[n][k]) so B-fragments are contiguous ds_read_b128.
// LDS row stride 40 (80B) breaks power-of-2 bank conflicts.
template <int K, int N, bool GATHER>
__global__ void gemm_layer(const float* __restrict__ Xf, const short* __restrict__ Ain,
                           const float* __restrict__ w0, const float* __restrict__ wc,
                           short* __restrict__ Aout,
                           const int* __restrict__ order,
                           const int* __restrict__ tile_c, const int* __restrict__ tile_r,
                           const int* __restrict__ meta) {
  const int bt = blockIdx.x;
  if (bt >= meta[0]) return;
  const int cl = tile_c[bt];
  const int row0 = tile_r[bt];
  const int n0 = blockIdx.y * 128;

  __shared__ short As[128 * 40];
  __shared__ short Bs[128 * 40];  // transposed: Bs[n][k]

  const int tid = threadIdx.x;
  const int lane = tid & 63;
  const int wm = (tid >> 6) >> 1;
  const int wn = (tid >> 6) & 1;

  f32x4 acc[4][4] = {};

  const int arow = tid >> 2;           // 0..63
  const int akseg = (tid & 3) << 3;    // 0,8,16,24
  const int bn = tid & 127;            // 0..127
  const int bkq = (tid >> 7) << 3;     // 0 or 8

  const float* xr0 = nullptr; const float* xr1 = nullptr;
  const short* ar0 = nullptr; const short* ar1 = nullptr;
  if (GATHER) {
    xr0 = Xf + (size_t)order[row0 + arow] * K + akseg;
    xr1 = Xf + (size_t)order[row0 + arow + 64] * K + akseg;
  } else {
    ar0 = Ain + (size_t)(row0 + arow) * K + akseg;
    ar1 = Ain + (size_t)(row0 + arow + 64) * K + akseg;
  }
  const float* w0p = w0 + n0 + bn;
  const float* wcp = wc + (size_t)cl * K * N + n0 + bn;

  for (int kb = 0; kb < K; kb += 32) {
    __syncthreads();
    if (GATHER) {
      float4 a = *(const float4*)(xr0 + kb);
      float4 b = *(const float4*)(xr0 + kb + 4);
      short8 v;
      v[0] = f2bf(a.x); v[1] = f2bf(a.y); v[2] = f2bf(a.z); v[3] = f2bf(a.w);
      v[4] = f2bf(b.x); v[5] = f2bf(b.y); v[6] = f2bf(b.z); v[7] = f2bf(b.w);
      *(short8*)&As[arow * 40 + akseg] = v;
      a = *(const float4*)(xr1 + kb);
      b = *(const float4*)(xr1 + kb + 4);
      v[0] = f2bf(a.x); v[1] = f2bf(a.y); v[2] = f2bf(a.z); v[3] = f2bf(a.w);
      v[4] = f2bf(b.x); v[5] = f2bf(b.y); v[6] = f2bf(b.z); v[7] = f2bf(b.w);
      *(short8*)&As[(arow + 64) * 40 + akseg] = v;
    } else {
      *(short8*)&As[arow * 40 + akseg] = *(const short8*)(ar0 + kb);
      *(short8*)&As[(arow + 64) * 40 + akseg] = *(const short8*)(ar1 + kb);
    }
#pragma unroll
    for (int half = 0; half < 2; ++half) {
      const int kk = bkq + half * 16;
      short8 v;
#pragma unroll
      for (int j = 0; j < 8; ++j) {
        const size_t off = (size_t)(kb + kk + j) * N;
        v[j] = f2bf(w0p[off] * wcp[off]);
      }
      *(short8*)&Bs[bn * 40 + kk] = v;
    }
    __syncthreads();

    const int arL = wm * 64 + (lane & 15);
    const int kq = (lane >> 4) << 3;
    const int bcL = wn * 64 + (lane & 15);
    short8 af[4], bfr[4];
#pragma unroll
    for (int mi = 0; mi < 4; ++mi) af[mi] = *(const short8*)&As[(arL + mi * 16) * 40 + kq];
#pragma unroll
    for (int ni = 0; ni < 4; ++ni) bfr[ni] = *(const short8*)&Bs[(bcL + ni * 16) * 40 + kq];
#pragma unroll
    for (int mi = 0; mi < 4; ++mi) {
#pragma unroll
      for (int ni = 0; ni < 4; ++ni) {
        acc[mi][ni] = __builtin_amdgcn_mfma_f32_16x16x32_bf16(
            __builtin_bit_cast(bf16x8, af[mi]), __builtin_bit_cast(bf16x8, bfr[ni]),
            acc[mi][ni], 0, 0, 0);
      }
    }
  }

  // epilogue: relu + bf16 store. C/D layout: col=lane&15, row=(lane>>4)*4+reg
  const int er = (lane >> 4) << 2;
  const int ec = lane & 15;
#pragma unroll
  for (int mi = 0; mi < 4; ++mi) {
#pragma unroll
    for (int ni = 0; ni < 4; ++ni) {
#pragma unroll
      for (int r = 0; r < 4; ++r) {
        float vv = fmaxf(acc[mi][ni][r], 0.f);
        const int row = row0 + wm * 64 + mi * 16 + er + r;
        const int col = n0 + wn * 64 + ni * 16 + ec;
        Aout[(size_t)row * N + col] = f2bf(vv);
      }
    }
  }
}

// final layer: z = h2 . (w0_3*wc_3[c]), sigmoid, scatter to original sample slot
__global__ void layer3_kernel(const short* __restrict__ h2, const float* __restrict__ w03,
                              const float* __restrict__ wc3, const int* __restrict__ order,
                              const int* __restrict__ pstart, const int* __restrict__ meta,
                              float* __restrict__ out) {
  const int r = blockIdx.x;
  if (r >= meta[1]) return;
  const int lane = threadIdx.x;
  int c = 0;
#pragma unroll
  for (int i = 1; i < CLN; ++i) { if (r >= pstart[i]) c = i; }
  const short* hr = h2 + (size_t)r * 512;
  const int k0 = lane * 8;
  const short8 hv = *(const short8*)(hr + k0);
  const float* wcr = wc3 + c * 512;
  float part = 0.f;
#pragma unroll
  for (int j = 0; j < 8; ++j) part += bf2f(hv[j]) * w03[k0 + j] * wcr[k0 + j];
  for (int off = 32; off; off >>= 1) part += __shfl_down(part, off);
  if (lane == 0) out[order[r]] = 1.f / (1.f + expf(-part));
}

extern "C" void kernel_launch(void* const* d_in, const int* in_sizes, int n_in,
                              void* d_out, int out_size, void* d_ws, size_t ws_size,
                              hipStream_t stream) {
  const float* x = (const float*)d_in[0];
  const float* center = (const float*)d_in[1];
  const float* w0s[4]; const float* wcs[4];
  if (in_sizes[3] == 8 * in_sizes[2]) {  // dict order: w0_i, wc_i interleaved
    for (int i = 0; i < 4; ++i) { w0s[i] = (const float*)d_in[2 + 2 * i]; wcs[i] = (const float*)d_in[3 + 2 * i]; }
  } else {                               // signature order: w0_0..w0_3, wc_0..wc_3
    for (int i = 0; i < 4; ++i) { w0s[i] = (const float*)d_in[2 + i]; wcs[i] = (const float*)d_in[6 + i]; }
  }
  float* out = (float*)d_out;
  char* ws = (char*)d_ws;
  int* counts = (int*)(ws + 0);
  int* cursor = (int*)(ws + 64);
  int* pstart = (int*)(ws + 128);    // 9 ints
  int* meta   = (int*)(ws + 192);    // [n_tiles, padded_total]
  int* tile_c = (int*)(ws + 256);    // up to MAX_TILES
  int* tile_r = (int*)(ws + 1024);
  int* router = (int*)(ws + 2048);               // 8192 ints
  int* order  = (int*)(ws + 2048 + 4 * B_SZ);    // 9216 ints
  short* h0 = (short*)(ws + 131072);             // [PADMAX][2048] bf16
  short* h1 = h0 + (size_t)PADMAX * 2048;        // [PADMAX][1024] bf16
  short* h2 = h1 + (size_t)PADMAX * 1024;        // [PADMAX][512]  bf16
  // total ws use: ~66.2 MB

  zero_kernel<<<1, 64, 0, stream>>>(counts);
  router_kernel<<<B_SZ, 64, 0, stream>>>(x, center, router, counts);
  scan_kernel<<<1, 64, 0, stream>>>(counts, pstart, meta, tile_c, tile_r, cursor);
  scatter_kernel<<<B_SZ / 256, 256, 0, stream>>>(router, pstart, cursor, order);
  fillpad_kernel<<<PADMAX / 256, 256, 0, stream>>>(counts, pstart, order);

  gemm_layer<1024, 2048, true><<<dim3(MAX_TILES, 16), 256, 0, stream>>>(
      x, nullptr, w0s[0], wcs[0], h0, order, tile_c, tile_r, meta);
  gemm_layer<2048, 1024, false><<<dim3(MAX_TILES, 8), 256, 0, stream>>>(
      nullptr, h0, w0s[1], wcs[1], h1, order, tile_c, tile_r, meta);
  gemm_layer<1024, 512, false><<<dim3(MAX_TILES, 4), 256, 0, stream>>>(
      nullptr, h1, w0s[2], wcs[2], h2, order, tile_c, tile_r, meta);
  layer3_kernel<<<PADMAX, 64, 0, stream>>>(h2, w0s[3], wcs[3], order, pstart, meta, out);
}

// Round 2
// 543.540 us; speedup vs baseline: 1.2807x; 1.2807x over previous
//
#include <hip/hip_runtime.h>
#include <hip/hip_bf16.h>

#define B_SZ 8192
#define DIMS 1024
#define CLN 8
#define BM 128
#define PADMAX (B_SZ + CLN * BM)     // 9216
#define MAX_TILES (B_SZ / BM + CLN)  // 72

typedef __attribute__((ext_vector_type(8))) __bf16 bf16x8;
typedef __attribute__((ext_vector_type(8))) short short8;
typedef __attribute__((ext_vector_type(4))) float f32x4;

__device__ __forceinline__ short f2bf(float f) {
  __hip_bfloat16 h = __float2bfloat16(f);
  return __builtin_bit_cast(short, h);
}
__device__ __forceinline__ float bf2f(short s) {
  unsigned u = ((unsigned)(unsigned short)s) << 16;
  return __builtin_bit_cast(float, u);
}

__global__ void zero_kernel(int* counts) {
  if (threadIdx.x < CLN) counts[threadIdx.x] = 0;
}

// one wave per sample: sij = x . center[c], argmax (first max wins, like jnp.argmax)
__global__ void router_kernel(const float* __restrict__ x, const float* __restrict__ center,
                              int* __restrict__ router, int* __restrict__ counts) {
  const int s = blockIdx.x;
  const int lane = threadIdx.x;
  const float* xr = x + (size_t)s * DIMS;
  float p[CLN];
#pragma unroll
  for (int c = 0; c < CLN; ++c) p[c] = 0.f;
  for (int t = 0; t < DIMS / 64; ++t) {
    const int i = lane + t * 64;
    const float xv = xr[i];
#pragma unroll
    for (int c = 0; c < CLN; ++c) p[c] += xv * center[c * DIMS + i];
  }
#pragma unroll
  for (int c = 0; c < CLN; ++c) {
    for (int off = 32; off; off >>= 1) p[c] += __shfl_down(p[c], off);
  }
  if (lane == 0) {
    int best = 0; float bv = p[0];
#pragma unroll
    for (int c = 1; c < CLN; ++c) { if (p[c] > bv) { bv = p[c]; best = c; } }
    router[s] = best;
    atomicAdd(&counts[best], 1);
  }
}

// single thread: padded per-cluster ranges (multiple of BM) + tile table
__global__ void scan_kernel(const int* __restrict__ counts, int* padded_start, int* meta,
                            int* tile_c, int* tile_r, int* cursor) {
  if (threadIdx.x != 0 || blockIdx.x != 0) return;
  int ps = 0, nt = 0;
  for (int c = 0; c < CLN; ++c) {
    padded_start[c] = ps;
    cursor[c] = 0;
    const int t = (counts[c] + BM - 1) / BM;
    for (int i = 0; i < t; ++i) { tile_c[nt] = c; tile_r[nt] = ps + i * BM; ++nt; }
    ps += t * BM;
  }
  padded_start[CLN] = ps;
  meta[0] = nt;  // n_tiles
  meta[1] = ps;  // padded_total
}

__global__ void scatter_kernel(const int* __restrict__ router, const int* __restrict__ pstart,
                               int* __restrict__ cursor, int* __restrict__ order) {
  const int s = blockIdx.x * blockDim.x + threadIdx.x;
  if (s >= B_SZ) return;
  const int c = router[s];
  const int pos = pstart[c] + atomicAdd(&cursor[c], 1);
  order[pos] = s;
}

// fill padding slots with a duplicate valid sample of the same cluster
__global__ void fillpad_kernel(const int* __restrict__ counts, const int* __restrict__ pstart,
                               int* __restrict__ order) {
  const int p = blockIdx.x * blockDim.x + threadIdx.x;
  if (p >= PADMAX) return;
#pragma unroll
  for (int c = 0; c < CLN; ++c) {
    if (p >= pstart[c] && p < pstart[c + 1]) {
      const int idx = p - pstart[c];
      if (idx >= counts[c]) order[p] = order[pstart[c]];
      break;
    }
  }
}

// -------- pre-gating pass: gwt[c][n][k] = bf16(w0[k][n] * wc[c][k][n]) --------
// tile 32k x 64n per block, LDS transpose (pad 65 to break bank conflicts)
template <int K, int N>
__global__ void gate_kernel(const float* __restrict__ w0, const float* __restrict__ wc,
                            short* __restrict__ gwt) {
  const int k0 = blockIdx.x * 32;
  const int n0 = blockIdx.y * 64;
  const int c = blockIdx.z;
  __shared__ short t[32 * 65];
  const int tid = threadIdx.x;
  const int lk = tid >> 4;          // 0..15
  const int ln = (tid & 15) * 4;    // 0,4,..,60
  const float* w0p = w0 + (size_t)k0 * N + n0;
  const float* wcp = wc + (size_t)c * K * N + (size_t)k0 * N + n0;
#pragma unroll
  for (int i = 0; i < 2; ++i) {
    const int k = lk + i * 16;
    float4 a = *(const float4*)(w0p + (size_t)k * N + ln);
    float4 b = *(const float4*)(wcp + (size_t)k * N + ln);
    short* d = &t[k * 65 + ln];
    d[0] = f2bf(a.x * b.x); d[1] = f2bf(a.y * b.y);
    d[2] = f2bf(a.z * b.z); d[3] = f2bf(a.w * b.w);
  }
  __syncthreads();
  const int wn = tid >> 2;          // 0..63
  const int wk = (tid & 3) * 8;     // 0,8,16,24
  short8 v;
#pragma unroll
  for (int j = 0; j < 8; ++j) v[j] = t[(wk + j) * 65 + wn];
  *(short8*)(gwt + ((size_t)c * N + n0 + wn) * K + k0 + wk) = v;
}

// -------- fast GEMM: pure bf16, pre-gated transposed weights --------
// 128x128 tile, 4 waves (2x2 of 64x64), mfma_f32_16x16x32_bf16.
// A: [row][k] bf16 (layer0 gathers fp32 x via order[]), B: gwt[c][n][k] bf16.
// LDS row stride 40 shorts (80B) breaks power-of-2 bank conflicts.
template <int K, int N, bool GATHER>
__global__ void gemm_fast(const float* __restrict__ Xf, const short* __restrict__ Ain,
                          const short* __restrict__ gwt, short* __restrict__ Aout,
                          const int* __restrict__ order,
                          const int* __restrict__ tile_c, const int* __restrict__ tile_r,
                          const int* __restrict__ meta) {
  const int bt = blockIdx.x;
  if (bt >= meta[0]) return;
  const int cl = tile_c[bt];
  const int row0 = tile_r[bt];
  const int n0 = blockIdx.y * 128;

  __shared__ short As[128 * 40];
  __shared__ short Bs[128 * 40];  // Bs[n][k]

  const int tid = threadIdx.x;
  const int lane = tid & 63;
  const int wm = (tid >> 6) >> 1;
  const int wn = (tid >> 6) & 1;

  f32x4 acc[4][4] = {};

  const int srow = tid >> 2;         // 0..63
  const int skseg = (tid & 3) << 3;  // 0,8,16,24

  const float* xr0 = nullptr; const float* xr1 = nullptr;
  const short* ar0 = nullptr; const short* ar1 = nullptr;
  if (GATHER) {
    xr0 = Xf + (size_t)order[row0 + srow] * K + skseg;
    xr1 = Xf + (size_t)order[row0 + srow + 64] * K + skseg;
  } else {
    ar0 = Ain + (size_t)(row0 + srow) * K + skseg;
    ar1 = Ain + (size_t)(row0 + srow + 64) * K + skseg;
  }
  const short* bp0 = gwt + ((size_t)cl * N + n0 + srow) * K + skseg;
  const short* bp1 = bp0 + (size_t)64 * K;

  for (int kb = 0; kb < K; kb += 32) {
    __syncthreads();
    if (GATHER) {
      float4 a = *(const float4*)(xr0 + kb);
      float4 b = *(const float4*)(xr0 + kb + 4);
      short8 v;
      v[0] = f2bf(a.x); v[1] = f2bf(a.y); v[2] = f2bf(a.z); v[3] = f2bf(a.w);
      v[4] = f2bf(b.x); v[5] = f2bf(b.y); v[6] = f2bf(b.z); v[7] = f2bf(b.w);
      *(short8*)&As[srow * 40 + skseg] = v;
      a = *(const float4*)(xr1 + kb);
      b = *(const float4*)(xr1 + kb + 4);
      v[0] = f2bf(a.x); v[1] = f2bf(a.y); v[2] = f2bf(a.z); v[3] = f2bf(a.w);
      v[4] = f2bf(b.x); v[5] = f2bf(b.y); v[6] = f2bf(b.z); v[7] = f2bf(b.w);
      *(short8*)&As[(srow + 64) * 40 + skseg] = v;
    } else {
      *(short8*)&As[srow * 40 + skseg] = *(const short8*)(ar0 + kb);
      *(short8*)&As[(srow + 64) * 40 + skseg] = *(const short8*)(ar1 + kb);
    }
    *(short8*)&Bs[srow * 40 + skseg] = *(const short8*)(bp0 + kb);
    *(short8*)&Bs[(srow + 64) * 40 + skseg] = *(const short8*)(bp1 + kb);
    __syncthreads();

    const int arL = wm * 64 + (lane & 15);
    const int kq = (lane >> 4) << 3;
    const int bcL = wn * 64 + (lane & 15);
    short8 af[4], bfr[4];
#pragma unroll
    for (int mi = 0; mi < 4; ++mi) af[mi] = *(const short8*)&As[(arL + mi * 16) * 40 + kq];
#pragma unroll
    for (int ni = 0; ni < 4; ++ni) bfr[ni] = *(const short8*)&Bs[(bcL + ni * 16) * 40 + kq];
#pragma unroll
    for (int mi = 0; mi < 4; ++mi) {
#pragma unroll
      for (int ni = 0; ni < 4; ++ni) {
        acc[mi][ni] = __builtin_amdgcn_mfma_f32_16x16x32_bf16(
            __builtin_bit_cast(bf16x8, af[mi]), __builtin_bit_cast(bf16x8, bfr[ni]),
            acc[mi][ni], 0, 0, 0);
      }
    }
  }

  // epilogue: relu + bf16 store. C/D layout: col=lane&15, row=(lane>>4)*4+reg
  const int er = (lane >> 4) << 2;
  const int ec = lane & 15;
#pragma unroll
  for (int mi = 0; mi < 4; ++mi) {
#pragma unroll
    for (int ni = 0; ni < 4; ++ni) {
#pragma unroll
      for (int r = 0; r < 4; ++r) {
        float vv = fmaxf(acc[mi][ni][r], 0.f);
        const int row = row0 + wm * 64 + mi * 16 + er + r;
        const int col = n0 + wn * 64 + ni * 16 + ec;
        Aout[(size_t)row * N + col] = f2bf(vv);
      }
    }
  }
}

// -------- fallback GEMM (round-1): gating fused in staging, fp32 weights --------
template <int K, int N, bool GATHER>
__global__ void gemm_layer(const float* __restrict__ Xf, const short* __restrict__ Ain,
                           const float* __restrict__ w0, const float* __restrict__ wc,
                           short* __restrict__ Aout,
                           const int* __restrict__ order,
                           const int* __restrict__ tile_c, const int* __restrict__ tile_r,
                           const int* __restrict__ meta) {
  const int bt = blockIdx.x;
  if (bt >= meta[0]) return;
  const int cl = tile_c[bt];
  const int row0 = tile_r[bt];
  const int n0 = blockIdx.y * 128;

  __shared__ short As[128 * 40];
  __shared__ short Bs[128 * 40];

  const int tid = threadIdx.x;
  const int lane = tid & 63;
  const int wm = (tid >> 6) >> 1;
  const int wn = (tid >> 6) & 1;

  f32x4 acc[4][4] = {};

  const int arow = tid >> 2;
  const int akseg = (tid & 3) << 3;
  const int bn = tid & 127;
  const int bkq = (tid >> 7) << 3;

  const float* xr0 = nullptr; const float* xr1 = nullptr;
  const short* ar0 = nullptr; const short* ar1 = nullptr;
  if (GATHER) {
    xr0 = Xf + (size_t)order[row0 + arow] * K + akseg;
    xr1 = Xf + (size_t)order[row0 + arow + 64] * K + akseg;
  } else {
    ar0 = Ain + (size_t)(row0 + arow) * K + akseg;
    ar1 = Ain + (size_t)(row0 + arow + 64) * K + akseg;
  }
  const float* w0p = w0 + n0 + bn;
  const float* wcp = wc + (size_t)cl * K * N + n0 + bn;

  for (int kb = 0; kb < K; kb += 32) {
    __syncthreads();
    if (GATHER) {
      float4 a = *(const float4*)(xr0 + kb);
      float4 b = *(const float4*)(xr0 + kb + 4);
      short8 v;
      v[0] = f2bf(a.x); v[1] = f2bf(a.y); v[2] = f2bf(a.z); v[3] = f2bf(a.w);
      v[4] = f2bf(b.x); v[5] = f2bf(b.y); v[6] = f2bf(b.z); v[7] = f2bf(b.w);
      *(short8*)&As[arow * 40 + akseg] = v;
      a = *(const float4*)(xr1 + kb);
      b = *(const float4*)(xr1 + kb + 4);
      v[0] = f2bf(a.x); v[1] = f2bf(a.y); v[2] = f2bf(a.z); v[3] = f2bf(a.w);
      v[4] = f2bf(b.x); v[5] = f2bf(b.y); v[6] = f2bf(b.z); v[7] = f2bf(b.w);
      *(short8*)&As[(arow + 64) * 40 + akseg] = v;
    } else {
      *(short8*)&As[arow * 40 + akseg] = *(const short8*)(ar0 + kb);
      *(short8*)&As[(arow + 64) * 40 + akseg] = *(const short8*)(ar1 + kb);
    }
#pragma unroll
    for (int half = 0; half < 2; ++half) {
      const int kk = bkq + half * 16;
      short8 v;
#pragma unroll
      for (int j = 0; j < 8; ++j) {
        const size_t off = (size_t)(kb + kk + j) * N;
        v[j] = f2bf(w0p[off] * wcp[off]);
      }
      *(short8*)&Bs[bn * 40 + kk] = v;
    }
    __syncthreads();

    const int arL = wm * 64 + (lane & 15);
    const int kq = (lane >> 4) << 3;
    const int bcL = wn * 64 + (lane & 15);
    short8 af[4], bfr[4];
#pragma unroll
    for (int mi = 0; mi < 4; ++mi) af[mi] = *(const short8*)&As[(arL + mi * 16) * 40 + kq];
#pragma unroll
    for (int ni = 0; ni < 4; ++ni) bfr[ni] = *(const short8*)&Bs[(bcL + ni * 16) * 40 + kq];
#pragma unroll
    for (int mi = 0; mi < 4; ++mi) {
#pragma unroll
      for (int ni = 0; ni < 4; ++ni) {
        acc[mi][ni] = __builtin_amdgcn_mfma_f32_16x16x32_bf16(
            __builtin_bit_cast(bf16x8, af[mi]), __builtin_bit_cast(bf16x8, bfr[ni]),
            acc[mi][ni], 0, 0, 0);
      }
    }
  }

  const int er = (lane >> 4) << 2;
  const int ec = lane & 15;
#pragma unroll
  for (int mi = 0; mi < 4; ++mi) {
#pragma unroll
    for (int ni = 0; ni < 4; ++ni) {
#pragma unroll
      for (int r = 0; r < 4; ++r) {
        float vv = fmaxf(acc[mi][ni][r], 0.f);
        const int row = row0 + wm * 64 + mi * 16 + er + r;
        const int col = n0 + wn * 64 + ni * 16 + ec;
        Aout[(size_t)row * N + col] = f2bf(vv);
      }
    }
  }
}

// final layer: z = h2 . (w0_3*wc_3[c]), sigmoid, scatter to original sample slot
__global__ void layer3_kernel(const short* __restrict__ h2, const float* __restrict__ w03,
                              const float* __restrict__ wc3, const int* __restrict__ order,
                              const int* __restrict__ pstart, const int* __restrict__ meta,
                              float* __restrict__ out) {
  const int r = blockIdx.x;
  if (r >= meta[1]) return;
  const int lane = threadIdx.x;
  int c = 0;
#pragma unroll
  for (int i = 1; i < CLN; ++i) { if (r >= pstart[i]) c = i; }
  const short* hr = h2 + (size_t)r * 512;
  const int k0 = lane * 8;
  const short8 hv = *(const short8*)(hr + k0);
  const float* wcr = wc3 + c * 512;
  float part = 0.f;
#pragma unroll
  for (int j = 0; j < 8; ++j) part += bf2f(hv[j]) * w03[k0 + j] * wcr[k0 + j];
  for (int off = 32; off; off >>= 1) part += __shfl_down(part, off);
  if (lane == 0) out[order[r]] = 1.f / (1.f + expf(-part));
}

extern "C" void kernel_launch(void* const* d_in, const int* in_sizes, int n_in,
                              void* d_out, int out_size, void* d_ws, size_t ws_size,
                              hipStream_t stream) {
  const float* x = (const float*)d_in[0];
  const float* center = (const float*)d_in[1];
  const float* w0s[4]; const float* wcs[4];
  if (in_sizes[3] == 8 * in_sizes[2]) {  // dict order: w0_i, wc_i interleaved
    for (int i = 0; i < 4; ++i) { w0s[i] = (const float*)d_in[2 + 2 * i]; wcs[i] = (const float*)d_in[3 + 2 * i]; }
  } else {                               // signature order: w0_0..w0_3, wc_0..wc_3
    for (int i = 0; i < 4; ++i) { w0s[i] = (const float*)d_in[2 + i]; wcs[i] = (const float*)d_in[6 + i]; }
  }
  float* out = (float*)d_out;
  char* ws = (char*)d_ws;
  int* counts = (int*)(ws + 0);
  int* cursor = (int*)(ws + 64);
  int* pstart = (int*)(ws + 128);
  int* meta   = (int*)(ws + 192);
  int* tile_c = (int*)(ws + 256);
  int* tile_r = (int*)(ws + 1024);
  int* router = (int*)(ws + 2048);
  int* order  = (int*)(ws + 2048 + 4 * B_SZ);

  zero_kernel<<<1, 64, 0, stream>>>(counts);
  router_kernel<<<B_SZ, 64, 0, stream>>>(x, center, router, counts);
  scan_kernel<<<1, 64, 0, stream>>>(counts, pstart, meta, tile_c, tile_r, cursor);
  scatter_kernel<<<B_SZ / 256, 256, 0, stream>>>(router, pstart, cursor, order);
  fillpad_kernel<<<PADMAX / 256, 256, 0, stream>>>(counts, pstart, order);

  const size_t GW_BYTES = (size_t)CLN * 2048 * 1024 * 2;      // 32 MB (max layer)
  const size_t H0_BYTES = (size_t)PADMAX * 2048 * 2;          // 37.75 MB
  const size_t H1_BYTES = (size_t)PADMAX * 1024 * 2;          // 18.87 MB
  const size_t NEED = 131072 + GW_BYTES + H0_BYTES + H1_BYTES;

  if (ws_size >= NEED) {
    // fast path: pre-gated bf16 transposed weights, reused gw buffer;
    // h2 overlaid on h0 (dead after gemm1)
    short* gw = (short*)(ws + 131072);
    short* h0 = (short*)(ws + 131072 + GW_BYTES);
    short* h1 = (short*)(ws + 131072 + GW_BYTES + H0_BYTES);
    short* h2 = h0;

    gate_kernel<1024, 2048><<<dim3(32, 32, CLN), 256, 0, stream>>>(w0s[0], wcs[0], gw);
    gemm_fast<1024, 2048, true><<<dim3(MAX_TILES, 16), 256, 0, stream>>>(
        x, nullptr, gw, h0, order, tile_c, tile_r, meta);
    gate_kernel<2048, 1024><<<dim3(64, 16, CLN), 256, 0, stream>>>(w0s[1], wcs[1], gw);
    gemm_fast<2048, 1024, false><<<dim3(MAX_TILES, 8), 256, 0, stream>>>(
        nullptr, h0, gw, h1, order, tile_c, tile_r, meta);
    gate_kernel<1024, 512><<<dim3(32, 8, CLN), 256, 0, stream>>>(w0s[2], wcs[2], gw);
    gemm_fast<1024, 512, false><<<dim3(MAX_TILES, 4), 256, 0, stream>>>(
        nullptr, h1, gw, h2, order, tile_c, tile_r, meta);
    layer3_kernel<<<PADMAX, 64, 0, stream>>>(h2, w0s[3], wcs[3], order, pstart, meta, out);
  } else {
    // fallback: round-1 fused-gating path (needs only ~66 MB)
    short* h0 = (short*)(ws + 131072);
    short* h1 = h0 + (size_t)PADMAX * 2048;
    short* h2 = h1 + (size_t)PADMAX * 1024;
    gemm_layer<1024, 2048, true><<<dim3(MAX_TILES, 16), 256, 0, stream>>>(
        x, nullptr, w0s[0], wcs[0], h0, order, tile_c, tile_r, meta);
    gemm_layer<2048, 1024, false><<<dim3(MAX_TILES, 8), 256, 0, stream>>>(
        nullptr, h0, w0s[1], wcs[1], h1, order, tile_c, tile_r, meta);
    gemm_layer<1024, 512, false><<<dim3(MAX_TILES, 4), 256, 0, stream>>>(
        nullptr, h1, w0s[2], wcs[2], h2, order, tile_c, tile_r, meta);
    layer3_kernel<<<PADMAX, 64, 0, stream>>>(h2, w0s[3], wcs[3], order, pstart, meta, out);
  }
}

// Round 3
// 518.181 us; speedup vs baseline: 1.3433x; 1.0489x over previous
//
#include <hip/hip_runtime.h>
#include <hip/hip_bf16.h>

#define B_SZ 8192
#define DIMS 1024
#define CLN 8
#define BM 128
#define PADMAX (B_SZ + CLN * BM)     // 9216
#define MAX_TILES (B_SZ / BM + CLN)  // 72

typedef __attribute__((ext_vector_type(8))) __bf16 bf16x8;
typedef __attribute__((ext_vector_type(8))) short short8;
typedef __attribute__((ext_vector_type(4))) short short4v;
typedef __attribute__((ext_vector_type(4))) float f32x4;

__device__ __forceinline__ short f2bf(float f) {
  __hip_bfloat16 h = __float2bfloat16(f);
  return __builtin_bit_cast(short, h);
}
__device__ __forceinline__ float bf2f(short s) {
  unsigned u = ((unsigned)(unsigned short)s) << 16;
  return __builtin_bit_cast(float, u);
}

// async 16B/lane global->LDS DMA. LDS dest must be wave-uniform base; HW adds lane*16.
__device__ __forceinline__ void gl_lds16(const short* g, short* l) {
  __builtin_amdgcn_global_load_lds(
      (const __attribute__((address_space(1))) unsigned int*)(unsigned long long)(uintptr_t)g,
      (__attribute__((address_space(3))) unsigned int*)(unsigned long long)(uintptr_t)l,
      16, 0, 0);
}

__global__ void zero_kernel(int* counts) {
  if (threadIdx.x < CLN) counts[threadIdx.x] = 0;
}

// 4 waves/block, 1 sample/wave. float4 x loads; fused fp32->bf16 conversion into xb.
__global__ void router_kernel(const float* __restrict__ x, const float* __restrict__ center,
                              int* __restrict__ router, int* __restrict__ counts,
                              short* __restrict__ xb) {
  const int tid = threadIdx.x;
  const int lane = tid & 63;
  const int w = tid >> 6;
  const int s = blockIdx.x * 4 + w;
  const float4* xr = (const float4*)(x + (size_t)s * DIMS);
  float4 xv[4];
#pragma unroll
  for (int j = 0; j < 4; ++j) xv[j] = xr[j * 64 + lane];
  if (xb) {
    short* xbr = xb + (size_t)s * DIMS;
#pragma unroll
    for (int j = 0; j < 4; ++j) {
      short4v sv;
      sv[0] = f2bf(xv[j].x); sv[1] = f2bf(xv[j].y);
      sv[2] = f2bf(xv[j].z); sv[3] = f2bf(xv[j].w);
      *(short4v*)(xbr + j * 256 + lane * 4) = sv;
    }
  }
  float p[CLN];
#pragma unroll
  for (int c = 0; c < CLN; ++c) {
    const float4* cr = (const float4*)(center + (size_t)c * DIMS);
    float acc = 0.f;
#pragma unroll
    for (int j = 0; j < 4; ++j) {
      float4 cv = cr[j * 64 + lane];
      acc += xv[j].x * cv.x + xv[j].y * cv.y + xv[j].z * cv.z + xv[j].w * cv.w;
    }
    p[c] = acc;
  }
#pragma unroll
  for (int c = 0; c < CLN; ++c) {
#pragma unroll
    for (int m = 1; m < 64; m <<= 1) p[c] += __shfl_xor(p[c], m);
  }
  if (lane == 0) {
    int best = 0; float bv = p[0];
#pragma unroll
    for (int c = 1; c < CLN; ++c) { if (p[c] > bv) { bv = p[c]; best = c; } }
    router[s] = best;
    atomicAdd(&counts[best], 1);
  }
}

// single thread: padded per-cluster ranges (multiple of BM) + tile table
__global__ void scan_kernel(const int* __restrict__ counts, int* padded_start, int* meta,
                            int* tile_c, int* tile_r, int* cursor) {
  if (threadIdx.x != 0 || blockIdx.x != 0) return;
  int ps = 0, nt = 0;
  for (int c = 0; c < CLN; ++c) {
    padded_start[c] = ps;
    cursor[c] = 0;
    const int t = (counts[c] + BM - 1) / BM;
    for (int i = 0; i < t; ++i) { tile_c[nt] = c; tile_r[nt] = ps + i * BM; ++nt; }
    ps += t * BM;
  }
  padded_start[CLN] = ps;
  meta[0] = nt;  // n_tiles
  meta[1] = ps;  // padded_total
}

__global__ void scatter_kernel(const int* __restrict__ router, const int* __restrict__ pstart,
                               int* __restrict__ cursor, int* __restrict__ order) {
  const int s = blockIdx.x * blockDim.x + threadIdx.x;
  if (s >= B_SZ) return;
  const int c = router[s];
  const int pos = pstart[c] + atomicAdd(&cursor[c], 1);
  order[pos] = s;
}

// fill padding slots with a duplicate valid sample of the same cluster
__global__ void fillpad_kernel(const int* __restrict__ counts, const int* __restrict__ pstart,
                               int* __restrict__ order) {
  const int p = blockIdx.x * blockDim.x + threadIdx.x;
  if (p >= PADMAX) return;
#pragma unroll
  for (int c = 0; c < CLN; ++c) {
    if (p >= pstart[c] && p < pstart[c + 1]) {
      const int idx = p - pstart[c];
      if (idx >= counts[c]) order[p] = order[pstart[c]];
      break;
    }
  }
}

// -------- pre-gating pass: gwt[c][n][k] = bf16(w0[k][n] * wc[c][k][n]) --------
template <int K, int N>
__global__ void gate_kernel(const float* __restrict__ w0, const float* __restrict__ wc,
                            short* __restrict__ gwt) {
  const int k0 = blockIdx.x * 32;
  const int n0 = blockIdx.y * 64;
  const int c = blockIdx.z;
  __shared__ short t[32 * 65];
  const int tid = threadIdx.x;
  const int lk = tid >> 4;          // 0..15
  const int ln = (tid & 15) * 4;    // 0,4,..,60
  const float* w0p = w0 + (size_t)k0 * N + n0;
  const float* wcp = wc + (size_t)c * K * N + (size_t)k0 * N + n0;
#pragma unroll
  for (int i = 0; i < 2; ++i) {
    const int k = lk + i * 16;
    float4 a = *(const float4*)(w0p + (size_t)k * N + ln);
    float4 b = *(const float4*)(wcp + (size_t)k * N + ln);
    short* d = &t[k * 65 + ln];
    d[0] = f2bf(a.x * b.x); d[1] = f2bf(a.y * b.y);
    d[2] = f2bf(a.z * b.z); d[3] = f2bf(a.w * b.w);
  }
  __syncthreads();
  const int wn = tid >> 2;          // 0..63
  const int wk = (tid & 3) * 8;     // 0,8,16,24
  short8 v;
#pragma unroll
  for (int j = 0; j < 8; ++j) v[j] = t[(wk + j) * 65 + wn];
  *(short8*)(gwt + ((size_t)c * N + n0 + wn) * K + k0 + wk) = v;
}

// -------- m97-style GEMM: global_load_lds(16B) staging, pure bf16 --------
// 128x128 tile, 4 waves (2x2 of 64x64), mfma_f32_16x16x32_bf16, BK=32.
// LDS rows UNPADDED (32 shorts = 64B): required by global_load_lds lane ordering.
template <int K, int N, bool GATHER>
__global__ void gemm_async(const short* __restrict__ Abase, const short* __restrict__ gwt,
                           short* __restrict__ Aout, const int* __restrict__ order,
                           const int* __restrict__ tile_c, const int* __restrict__ tile_r,
                           const int* __restrict__ meta) {
  const int bt = blockIdx.x;
  if (bt >= meta[0]) return;
  const int cl = tile_c[bt];
  const int row0 = tile_r[bt];
  const int n0 = blockIdx.y * 128;

  __shared__ __align__(16) short As[128 * 32];
  __shared__ __align__(16) short Bs[128 * 32];  // Bs[n][k]

  const int tid = threadIdx.x;
  const int lane = tid & 63;
  const int w = tid >> 6;
  const int wm = w >> 1;
  const int wn = w & 1;

  // staging addresses: wave w covers rows [w*16, w*16+16); lane i -> row w*16+i/4, k-seg (i%4)*8
  const int lrow = lane >> 2;
  const int kofs = (lane & 3) << 3;
  const short* ga0;
  const short* ga1;
  if (GATHER) {
    ga0 = Abase + (size_t)order[row0 + w * 16 + lrow] * K + kofs;
    ga1 = Abase + (size_t)order[row0 + 64 + w * 16 + lrow] * K + kofs;
  } else {
    ga0 = Abase + (size_t)(row0 + w * 16 + lrow) * K + kofs;
    ga1 = ga0 + (size_t)64 * K;
  }
  const short* gb0 = gwt + ((size_t)cl * N + n0 + w * 16 + lrow) * K + kofs;
  const short* gb1 = gb0 + (size_t)64 * K;
  short* lA0 = &As[w * 16 * 32];        // wave-uniform LDS bases
  short* lA1 = &As[(64 + w * 16) * 32];
  short* lB0 = &Bs[w * 16 * 32];
  short* lB1 = &Bs[(64 + w * 16) * 32];

  f32x4 acc[4][4] = {};
  const int arL = wm * 64 + (lane & 15);
  const int bcL = wn * 64 + (lane & 15);
  const int kq = (lane >> 4) << 3;

  for (int kb = 0; kb < K; kb += 32) {
    __syncthreads();
    gl_lds16(ga0 + kb, lA0);
    gl_lds16(ga1 + kb, lA1);
    gl_lds16(gb0 + kb, lB0);
    gl_lds16(gb1 + kb, lB1);
    __syncthreads();  // compiler emits s_waitcnt vmcnt(0) before s_barrier

    short8 af[4], bfr[4];
#pragma unroll
    for (int mi = 0; mi < 4; ++mi) af[mi] = *(const short8*)&As[(arL + mi * 16) * 32 + kq];
#pragma unroll
    for (int ni = 0; ni < 4; ++ni) bfr[ni] = *(const short8*)&Bs[(bcL + ni * 16) * 32 + kq];
#pragma unroll
    for (int mi = 0; mi < 4; ++mi) {
#pragma unroll
      for (int ni = 0; ni < 4; ++ni) {
        acc[mi][ni] = __builtin_amdgcn_mfma_f32_16x16x32_bf16(
            __builtin_bit_cast(bf16x8, af[mi]), __builtin_bit_cast(bf16x8, bfr[ni]),
            acc[mi][ni], 0, 0, 0);
      }
    }
  }

  // epilogue: relu + bf16 store. C/D layout: col=lane&15, row=(lane>>4)*4+reg
  const int er = (lane >> 4) << 2;
  const int ec = lane & 15;
#pragma unroll
  for (int mi = 0; mi < 4; ++mi) {
#pragma unroll
    for (int ni = 0; ni < 4; ++ni) {
#pragma unroll
      for (int r = 0; r < 4; ++r) {
        float vv = fmaxf(acc[mi][ni][r], 0.f);
        const int row = row0 + wm * 64 + mi * 16 + er + r;
        const int col = n0 + wn * 64 + ni * 16 + ec;
        Aout[(size_t)row * N + col] = f2bf(vv);
      }
    }
  }
}

// -------- fallback GEMM (round-1): gating fused in staging, fp32 weights --------
template <int K, int N, bool GATHER>
__global__ void gemm_layer(const float* __restrict__ Xf, const short* __restrict__ Ain,
                           const float* __restrict__ w0, const float* __restrict__ wc,
                           short* __restrict__ Aout,
                           const int* __restrict__ order,
                           const int* __restrict__ tile_c, const int* __restrict__ tile_r,
                           const int* __restrict__ meta) {
  const int bt = blockIdx.x;
  if (bt >= meta[0]) return;
  const int cl = tile_c[bt];
  const int row0 = tile_r[bt];
  const int n0 = blockIdx.y * 128;

  __shared__ __align__(16) short As[128 * 40];
  __shared__ __align__(16) short Bs[128 * 40];

  const int tid = threadIdx.x;
  const int lane = tid & 63;
  const int wm = (tid >> 6) >> 1;
  const int wn = (tid >> 6) & 1;

  f32x4 acc[4][4] = {};

  const int arow = tid >> 2;
  const int akseg = (tid & 3) << 3;
  const int bn = tid & 127;
  const int bkq = (tid >> 7) << 3;

  const float* xr0 = nullptr; const float* xr1 = nullptr;
  const short* ar0 = nullptr; const short* ar1 = nullptr;
  if (GATHER) {
    xr0 = Xf + (size_t)order[row0 + arow] * K + akseg;
    xr1 = Xf + (size_t)order[row0 + arow + 64] * K + akseg;
  } else {
    ar0 = Ain + (size_t)(row0 + arow) * K + akseg;
    ar1 = Ain + (size_t)(row0 + arow + 64) * K + akseg;
  }
  const float* w0p = w0 + n0 + bn;
  const float* wcp = wc + (size_t)cl * K * N + n0 + bn;

  for (int kb = 0; kb < K; kb += 32) {
    __syncthreads();
    if (GATHER) {
      float4 a = *(const float4*)(xr0 + kb);
      float4 b = *(const float4*)(xr0 + kb + 4);
      short8 v;
      v[0] = f2bf(a.x); v[1] = f2bf(a.y); v[2] = f2bf(a.z); v[3] = f2bf(a.w);
      v[4] = f2bf(b.x); v[5] = f2bf(b.y); v[6] = f2bf(b.z); v[7] = f2bf(b.w);
      *(short8*)&As[arow * 40 + akseg] = v;
      a = *(const float4*)(xr1 + kb);
      b = *(const float4*)(xr1 + kb + 4);
      v[0] = f2bf(a.x); v[1] = f2bf(a.y); v[2] = f2bf(a.z); v[3] = f2bf(a.w);
      v[4] = f2bf(b.x); v[5] = f2bf(b.y); v[6] = f2bf(b.z); v[7] = f2bf(b.w);
      *(short8*)&As[(arow + 64) * 40 + akseg] = v;
    } else {
      *(short8*)&As[arow * 40 + akseg] = *(const short8*)(ar0 + kb);
      *(short8*)&As[(arow + 64) * 40 + akseg] = *(const short8*)(ar1 + kb);
    }
#pragma unroll
    for (int half = 0; half < 2; ++half) {
      const int kk = bkq + half * 16;
      short8 v;
#pragma unroll
      for (int j = 0; j < 8; ++j) {
        const size_t off = (size_t)(kb + kk + j) * N;
        v[j] = f2bf(w0p[off] * wcp[off]);
      }
      *(short8*)&Bs[bn * 40 + kk] = v;
    }
    __syncthreads();

    const int arL = wm * 64 + (lane & 15);
    const int kq = (lane >> 4) << 3;
    const int bcL = wn * 64 + (lane & 15);
    short8 af[4], bfr[4];
#pragma unroll
    for (int mi = 0; mi < 4; ++mi) af[mi] = *(const short8*)&As[(arL + mi * 16) * 40 + kq];
#pragma unroll
    for (int ni = 0; ni < 4; ++ni) bfr[ni] = *(const short8*)&Bs[(bcL + ni * 16) * 40 + kq];
#pragma unroll
    for (int mi = 0; mi < 4; ++mi) {
#pragma unroll
      for (int ni = 0; ni < 4; ++ni) {
        acc[mi][ni] = __builtin_amdgcn_mfma_f32_16x16x32_bf16(
            __builtin_bit_cast(bf16x8, af[mi]), __builtin_bit_cast(bf16x8, bfr[ni]),
            acc[mi][ni], 0, 0, 0);
      }
    }
  }

  const int er = (lane >> 4) << 2;
  const int ec = lane & 15;
#pragma unroll
  for (int mi = 0; mi < 4; ++mi) {
#pragma unroll
    for (int ni = 0; ni < 4; ++ni) {
#pragma unroll
      for (int r = 0; r < 4; ++r) {
        float vv = fmaxf(acc[mi][ni][r], 0.f);
        const int row = row0 + wm * 64 + mi * 16 + er + r;
        const int col = n0 + wn * 64 + ni * 16 + ec;
        Aout[(size_t)row * N + col] = f2bf(vv);
      }
    }
  }
}

// final layer: z = h2 . (w0_3*wc_3[c]), sigmoid, scatter. 4 waves/block, 1 row/wave.
__global__ void layer3_kernel(const short* __restrict__ h2, const float* __restrict__ w03,
                              const float* __restrict__ wc3, const int* __restrict__ order,
                              const int* __restrict__ pstart, const int* __restrict__ meta,
                              float* __restrict__ out) {
  const int tid = threadIdx.x;
  const int lane = tid & 63;
  const int w = tid >> 6;
  const int r = blockIdx.x * 4 + w;
  if (r >= meta[1]) return;
  int c = 0;
#pragma unroll
  for (int i = 1; i < CLN; ++i) { if (r >= pstart[i]) c = i; }
  const short* hr = h2 + (size_t)r * 512;
  const int k0 = lane * 8;
  const short8 hv = *(const short8*)(hr + k0);
  const float* wcr = wc3 + c * 512;
  float part = 0.f;
#pragma unroll
  for (int j = 0; j < 8; ++j) part += bf2f(hv[j]) * w03[k0 + j] * wcr[k0 + j];
  for (int off = 32; off; off >>= 1) part += __shfl_down(part, off);
  if (lane == 0) out[order[r]] = 1.f / (1.f + expf(-part));
}

extern "C" void kernel_launch(void* const* d_in, const int* in_sizes, int n_in,
                              void* d_out, int out_size, void* d_ws, size_t ws_size,
                              hipStream_t stream) {
  const float* x = (const float*)d_in[0];
  const float* center = (const float*)d_in[1];
  const float* w0s[4]; const float* wcs[4];
  if (in_sizes[3] == 8 * in_sizes[2]) {  // dict order: w0_i, wc_i interleaved
    for (int i = 0; i < 4; ++i) { w0s[i] = (const float*)d_in[2 + 2 * i]; wcs[i] = (const float*)d_in[3 + 2 * i]; }
  } else {                               // signature order: w0_0..w0_3, wc_0..wc_3
    for (int i = 0; i < 4; ++i) { w0s[i] = (const float*)d_in[2 + i]; wcs[i] = (const float*)d_in[6 + i]; }
  }
  float* out = (float*)d_out;
  char* ws = (char*)d_ws;
  int* counts = (int*)(ws + 0);
  int* cursor = (int*)(ws + 64);
  int* pstart = (int*)(ws + 128);
  int* meta   = (int*)(ws + 192);
  int* tile_c = (int*)(ws + 256);
  int* tile_r = (int*)(ws + 1024);
  int* router = (int*)(ws + 2048);
  int* order  = (int*)(ws + 2048 + 4 * B_SZ);

  const size_t GW_BYTES = (size_t)CLN * 2048 * 1024 * 2;      // 32 MB (max layer)
  const size_t H0_BYTES = (size_t)PADMAX * 2048 * 2;          // 37.75 MB
  const size_t H1_BYTES = (size_t)PADMAX * 1024 * 2;          // 18.87 MB (>= XB 16.8 MB)
  const size_t NEED = 131072 + GW_BYTES + H0_BYTES + H1_BYTES;
  const bool fast = (ws_size >= NEED);

  // xb overlays h1: xb lives router->gemm0, h1 lives gemm1->gemm2 (disjoint)
  short* gw = (short*)(ws + 131072);
  short* h0 = (short*)(ws + 131072 + GW_BYTES);
  short* h1 = (short*)(ws + 131072 + GW_BYTES + H0_BYTES);
  short* xb = fast ? h1 : nullptr;

  zero_kernel<<<1, 64, 0, stream>>>(counts);
  router_kernel<<<B_SZ / 4, 256, 0, stream>>>(x, center, router, counts, xb);
  scan_kernel<<<1, 64, 0, stream>>>(counts, pstart, meta, tile_c, tile_r, cursor);
  scatter_kernel<<<B_SZ / 256, 256, 0, stream>>>(router, pstart, cursor, order);
  fillpad_kernel<<<PADMAX / 256, 256, 0, stream>>>(counts, pstart, order);

  if (fast) {
    short* h2 = h0;  // h0 dead after gemm1

    gate_kernel<1024, 2048><<<dim3(32, 32, CLN), 256, 0, stream>>>(w0s[0], wcs[0], gw);
    gemm_async<1024, 2048, true><<<dim3(MAX_TILES, 16), 256, 0, stream>>>(
        xb, gw, h0, order, tile_c, tile_r, meta);
    gate_kernel<2048, 1024><<<dim3(64, 16, CLN), 256, 0, stream>>>(w0s[1], wcs[1], gw);
    gemm_async<2048, 1024, false><<<dim3(MAX_TILES, 8), 256, 0, stream>>>(
        h0, gw, h1, order, tile_c, tile_r, meta);
    gate_kernel<1024, 512><<<dim3(32, 8, CLN), 256, 0, stream>>>(w0s[2], wcs[2], gw);
    gemm_async<1024, 512, false><<<dim3(MAX_TILES, 4), 256, 0, stream>>>(
        h1, gw, h2, order, tile_c, tile_r, meta);
    layer3_kernel<<<(PADMAX + 3) / 4, 256, 0, stream>>>(h2, w0s[3], wcs[3], order, pstart, meta, out);
  } else {
    // fallback: round-1 fused-gating path (needs only ~66 MB)
    short* f0 = (short*)(ws + 131072);
    short* f1 = f0 + (size_t)PADMAX * 2048;
    short* f2 = f1 + (size_t)PADMAX * 1024;
    gemm_layer<1024, 2048, true><<<dim3(MAX_TILES, 16), 256, 0, stream>>>(
        x, nullptr, w0s[0], wcs[0], f0, order, tile_c, tile_r, meta);
    gemm_layer<2048, 1024, false><<<dim3(MAX_TILES, 8), 256, 0, stream>>>(
        nullptr, f0, w0s[1], wcs[1], f1, order, tile_c, tile_r, meta);
    gemm_layer<1024, 512, false><<<dim3(MAX_TILES, 4), 256, 0, stream>>>(
        nullptr, f1, w0s[2], wcs[2], f2, order, tile_c, tile_r, meta);
    layer3_kernel<<<(PADMAX + 3) / 4, 256, 0, stream>>>(f2, w0s[3], wcs[3], order, pstart, meta, out);
  }
}

// Round 4
// 406.585 us; speedup vs baseline: 1.7120x; 1.2745x over previous
//
#include <hip/hip_runtime.h>
#include <hip/hip_bf16.h>

#define B_SZ 8192
#define DIMS 1024
#define CLN 8
#define BM 128
#define PADMAX (B_SZ + CLN * BM)     // 9216
#define MAX_TILES (B_SZ / BM + CLN)  // 72
#define HB 32                        // histogram/scatter blocks (B_SZ/256)

typedef __attribute__((ext_vector_type(8))) __bf16 bf16x8;
typedef __attribute__((ext_vector_type(8))) short short8;
typedef __attribute__((ext_vector_type(4))) short short4v;
typedef __attribute__((ext_vector_type(4))) float f32x4;

__device__ __forceinline__ short f2bf(float f) {
  __hip_bfloat16 h = __float2bfloat16(f);
  return __builtin_bit_cast(short, h);
}
__device__ __forceinline__ float bf2f(short s) {
  unsigned u = ((unsigned)(unsigned short)s) << 16;
  return __builtin_bit_cast(float, u);
}

// async 16B/lane global->LDS DMA. LDS dest must be wave-uniform base; HW adds lane*16.
__device__ __forceinline__ void gl_lds16(const short* g, short* l) {
  __builtin_amdgcn_global_load_lds(
      (const __attribute__((address_space(1))) unsigned int*)(unsigned long long)(uintptr_t)g,
      (__attribute__((address_space(3))) unsigned int*)(unsigned long long)(uintptr_t)l,
      16, 0, 0);
}

// 4 waves/block, 1 sample/wave. float4 x loads; fused fp32->bf16 conversion into xb.
// NO global atomics (round-3 lesson: 8192 same-line atomicAdds serialized at ~13ns each).
__global__ void router_kernel(const float* __restrict__ x, const float* __restrict__ center,
                              int* __restrict__ router, short* __restrict__ xb) {
  const int tid = threadIdx.x;
  const int lane = tid & 63;
  const int w = tid >> 6;
  const int s = blockIdx.x * 4 + w;
  const float4* xr = (const float4*)(x + (size_t)s * DIMS);
  float4 xv[4];
#pragma unroll
  for (int j = 0; j < 4; ++j) xv[j] = xr[j * 64 + lane];
  if (xb) {
    short* xbr = xb + (size_t)s * DIMS;
#pragma unroll
    for (int j = 0; j < 4; ++j) {
      short4v sv;
      sv[0] = f2bf(xv[j].x); sv[1] = f2bf(xv[j].y);
      sv[2] = f2bf(xv[j].z); sv[3] = f2bf(xv[j].w);
      *(short4v*)(xbr + j * 256 + lane * 4) = sv;
    }
  }
  float p[CLN];
#pragma unroll
  for (int c = 0; c < CLN; ++c) {
    const float4* cr = (const float4*)(center + (size_t)c * DIMS);
    float acc = 0.f;
#pragma unroll
    for (int j = 0; j < 4; ++j) {
      float4 cv = cr[j * 64 + lane];
      acc += xv[j].x * cv.x + xv[j].y * cv.y + xv[j].z * cv.z + xv[j].w * cv.w;
    }
    p[c] = acc;
  }
#pragma unroll
  for (int c = 0; c < CLN; ++c) {
#pragma unroll
    for (int m = 1; m < 64; m <<= 1) p[c] += __shfl_xor(p[c], m);
  }
  if (lane == 0) {
    int best = 0; float bv = p[0];
#pragma unroll
    for (int c = 1; c < CLN; ++c) { if (p[c] > bv) { bv = p[c]; best = c; } }
    router[s] = best;
  }
}

// per-block histogram: LDS atomics only, plain global stores
__global__ void hist_kernel(const int* __restrict__ router, int* __restrict__ blockcnt) {
  __shared__ int bins[CLN];
  const int t = threadIdx.x;
  if (t < CLN) bins[t] = 0;
  __syncthreads();
  const int c = router[blockIdx.x * 256 + t];
  atomicAdd(&bins[c], 1);
  __syncthreads();
  if (t < CLN) blockcnt[blockIdx.x * CLN + t] = bins[t];
}

// single block: counts, padded starts, per-scatter-block bases, tile table.
// serial prefix walks LDS (no global-latency chain).
__global__ void scan_kernel(const int* __restrict__ blockcnt, int* __restrict__ counts,
                            int* __restrict__ pstart, int* __restrict__ meta,
                            int* __restrict__ tile_c, int* __restrict__ tile_r,
                            int* __restrict__ blockbase) {
  __shared__ int cnt[HB * CLN];
  __shared__ int base[HB * CLN];
  const int t = threadIdx.x;
  cnt[t] = blockcnt[t];
  __syncthreads();
  if (t == 0) {
    int ps = 0, nt = 0;
    for (int c = 0; c < CLN; ++c) {
      int tot = 0;
      for (int b = 0; b < HB; ++b) tot += cnt[b * CLN + c];
      pstart[c] = ps;
      counts[c] = tot;
      int run = ps;
      for (int b = 0; b < HB; ++b) { base[b * CLN + c] = run; run += cnt[b * CLN + c]; }
      const int tiles = (tot + BM - 1) / BM;
      for (int i = 0; i < tiles; ++i) { tile_c[nt] = c; tile_r[nt] = ps + i * BM; ++nt; }
      ps += tiles * BM;
    }
    pstart[CLN] = ps;
    meta[0] = nt;
    meta[1] = ps;
  }
  __syncthreads();
  blockbase[t] = base[t];
}

// scatter with LDS cursors + precomputed per-block bases: zero global atomics
__global__ void scatter_kernel(const int* __restrict__ router, const int* __restrict__ blockbase,
                               int* __restrict__ order) {
  __shared__ int cur[CLN];
  const int t = threadIdx.x;
  if (t < CLN) cur[t] = 0;
  __syncthreads();
  const int s = blockIdx.x * 256 + t;
  const int c = router[s];
  const int pos = blockbase[blockIdx.x * CLN + c] + atomicAdd(&cur[c], 1);
  order[pos] = s;
}

// fill padding slots with a duplicate valid sample of the same cluster
__global__ void fillpad_kernel(const int* __restrict__ counts, const int* __restrict__ pstart,
                               int* __restrict__ order) {
  const int p = blockIdx.x * blockDim.x + threadIdx.x;
  if (p >= PADMAX) return;
#pragma unroll
  for (int c = 0; c < CLN; ++c) {
    if (p >= pstart[c] && p < pstart[c + 1]) {
      const int idx = p - pstart[c];
      if (idx >= counts[c]) order[p] = order[pstart[c]];
      break;
    }
  }
}

// -------- pre-gating pass: gwt[c][n][k] = bf16(w0[k][n] * wc[c][k][n]) --------
template <int K, int N>
__global__ void gate_kernel(const float* __restrict__ w0, const float* __restrict__ wc,
                            short* __restrict__ gwt) {
  const int k0 = blockIdx.x * 32;
  const int n0 = blockIdx.y * 64;
  const int c = blockIdx.z;
  __shared__ short t[32 * 65];
  const int tid = threadIdx.x;
  const int lk = tid >> 4;          // 0..15
  const int ln = (tid & 15) * 4;    // 0,4,..,60
  const float* w0p = w0 + (size_t)k0 * N + n0;
  const float* wcp = wc + (size_t)c * K * N + (size_t)k0 * N + n0;
#pragma unroll
  for (int i = 0; i < 2; ++i) {
    const int k = lk + i * 16;
    float4 a = *(const float4*)(w0p + (size_t)k * N + ln);
    float4 b = *(const float4*)(wcp + (size_t)k * N + ln);
    short* d = &t[k * 65 + ln];
    d[0] = f2bf(a.x * b.x); d[1] = f2bf(a.y * b.y);
    d[2] = f2bf(a.z * b.z); d[3] = f2bf(a.w * b.w);
  }
  __syncthreads();
  const int wn = tid >> 2;          // 0..63
  const int wk = (tid & 3) * 8;     // 0,8,16,24
  short8 v;
#pragma unroll
  for (int j = 0; j < 8; ++j) v[j] = t[(wk + j) * 65 + wn];
  *(short8*)(gwt + ((size_t)c * N + n0 + wn) * K + k0 + wk) = v;
}

// -------- m97-style GEMM: global_load_lds(16B) staging, pure bf16 --------
// 128x128 tile, 4 waves (2x2 of 64x64), mfma_f32_16x16x32_bf16, BK=32.
// LDS rows UNPADDED (32 shorts = 64B): required by global_load_lds lane ordering.
template <int K, int N, bool GATHER>
__global__ void gemm_async(const short* __restrict__ Abase, const short* __restrict__ gwt,
                           short* __restrict__ Aout, const int* __restrict__ order,
                           const int* __restrict__ tile_c, const int* __restrict__ tile_r,
                           const int* __restrict__ meta) {
  const int bt = blockIdx.x;
  if (bt >= meta[0]) return;
  const int cl = tile_c[bt];
  const int row0 = tile_r[bt];
  const int n0 = blockIdx.y * 128;

  __shared__ __align__(16) short As[128 * 32];
  __shared__ __align__(16) short Bs[128 * 32];  // Bs[n][k]

  const int tid = threadIdx.x;
  const int lane = tid & 63;
  const int w = tid >> 6;
  const int wm = w >> 1;
  const int wn = w & 1;

  const int lrow = lane >> 2;
  const int kofs = (lane & 3) << 3;
  const short* ga0;
  const short* ga1;
  if (GATHER) {
    ga0 = Abase + (size_t)order[row0 + w * 16 + lrow] * K + kofs;
    ga1 = Abase + (size_t)order[row0 + 64 + w * 16 + lrow] * K + kofs;
  } else {
    ga0 = Abase + (size_t)(row0 + w * 16 + lrow) * K + kofs;
    ga1 = ga0 + (size_t)64 * K;
  }
  const short* gb0 = gwt + ((size_t)cl * N + n0 + w * 16 + lrow) * K + kofs;
  const short* gb1 = gb0 + (size_t)64 * K;
  short* lA0 = &As[w * 16 * 32];
  short* lA1 = &As[(64 + w * 16) * 32];
  short* lB0 = &Bs[w * 16 * 32];
  short* lB1 = &Bs[(64 + w * 16) * 32];

  f32x4 acc[4][4] = {};
  const int arL = wm * 64 + (lane & 15);
  const int bcL = wn * 64 + (lane & 15);
  const int kq = (lane >> 4) << 3;

  for (int kb = 0; kb < K; kb += 32) {
    __syncthreads();
    gl_lds16(ga0 + kb, lA0);
    gl_lds16(ga1 + kb, lA1);
    gl_lds16(gb0 + kb, lB0);
    gl_lds16(gb1 + kb, lB1);
    __syncthreads();

    short8 af[4], bfr[4];
#pragma unroll
    for (int mi = 0; mi < 4; ++mi) af[mi] = *(const short8*)&As[(arL + mi * 16) * 32 + kq];
#pragma unroll
    for (int ni = 0; ni < 4; ++ni) bfr[ni] = *(const short8*)&Bs[(bcL + ni * 16) * 32 + kq];
#pragma unroll
    for (int mi = 0; mi < 4; ++mi) {
#pragma unroll
      for (int ni = 0; ni < 4; ++ni) {
        acc[mi][ni] = __builtin_amdgcn_mfma_f32_16x16x32_bf16(
            __builtin_bit_cast(bf16x8, af[mi]), __builtin_bit_cast(bf16x8, bfr[ni]),
            acc[mi][ni], 0, 0, 0);
      }
    }
  }

  const int er = (lane >> 4) << 2;
  const int ec = lane & 15;
#pragma unroll
  for (int mi = 0; mi < 4; ++mi) {
#pragma unroll
    for (int ni = 0; ni < 4; ++ni) {
#pragma unroll
      for (int r = 0; r < 4; ++r) {
        float vv = fmaxf(acc[mi][ni][r], 0.f);
        const int row = row0 + wm * 64 + mi * 16 + er + r;
        const int col = n0 + wn * 64 + ni * 16 + ec;
        Aout[(size_t)row * N + col] = f2bf(vv);
      }
    }
  }
}

// -------- fallback GEMM (round-1): gating fused in staging, fp32 weights --------
template <int K, int N, bool GATHER>
__global__ void gemm_layer(const float* __restrict__ Xf, const short* __restrict__ Ain,
                           const float* __restrict__ w0, const float* __restrict__ wc,
                           short* __restrict__ Aout,
                           const int* __restrict__ order,
                           const int* __restrict__ tile_c, const int* __restrict__ tile_r,
                           const int* __restrict__ meta) {
  const int bt = blockIdx.x;
  if (bt >= meta[0]) return;
  const int cl = tile_c[bt];
  const int row0 = tile_r[bt];
  const int n0 = blockIdx.y * 128;

  __shared__ __align__(16) short As[128 * 40];
  __shared__ __align__(16) short Bs[128 * 40];

  const int tid = threadIdx.x;
  const int lane = tid & 63;
  const int wm = (tid >> 6) >> 1;
  const int wn = (tid >> 6) & 1;

  f32x4 acc[4][4] = {};

  const int arow = tid >> 2;
  const int akseg = (tid & 3) << 3;
  const int bn = tid & 127;
  const int bkq = (tid >> 7) << 3;

  const float* xr0 = nullptr; const float* xr1 = nullptr;
  const short* ar0 = nullptr; const short* ar1 = nullptr;
  if (GATHER) {
    xr0 = Xf + (size_t)order[row0 + arow] * K + akseg;
    xr1 = Xf + (size_t)order[row0 + arow + 64] * K + akseg;
  } else {
    ar0 = Ain + (size_t)(row0 + arow) * K + akseg;
    ar1 = Ain + (size_t)(row0 + arow + 64) * K + akseg;
  }
  const float* w0p = w0 + n0 + bn;
  const float* wcp = wc + (size_t)cl * K * N + n0 + bn;

  for (int kb = 0; kb < K; kb += 32) {
    __syncthreads();
    if (GATHER) {
      float4 a = *(const float4*)(xr0 + kb);
      float4 b = *(const float4*)(xr0 + kb + 4);
      short8 v;
      v[0] = f2bf(a.x); v[1] = f2bf(a.y); v[2] = f2bf(a.z); v[3] = f2bf(a.w);
      v[4] = f2bf(b.x); v[5] = f2bf(b.y); v[6] = f2bf(b.z); v[7] = f2bf(b.w);
      *(short8*)&As[arow * 40 + akseg] = v;
      a = *(const float4*)(xr1 + kb);
      b = *(const float4*)(xr1 + kb + 4);
      v[0] = f2bf(a.x); v[1] = f2bf(a.y); v[2] = f2bf(a.z); v[3] = f2bf(a.w);
      v[4] = f2bf(b.x); v[5] = f2bf(b.y); v[6] = f2bf(b.z); v[7] = f2bf(b.w);
      *(short8*)&As[(arow + 64) * 40 + akseg] = v;
    } else {
      *(short8*)&As[arow * 40 + akseg] = *(const short8*)(ar0 + kb);
      *(short8*)&As[(arow + 64) * 40 + akseg] = *(const short8*)(ar1 + kb);
    }
#pragma unroll
    for (int half = 0; half < 2; ++half) {
      const int kk = bkq + half * 16;
      short8 v;
#pragma unroll
      for (int j = 0; j < 8; ++j) {
        const size_t off = (size_t)(kb + kk + j) * N;
        v[j] = f2bf(w0p[off] * wcp[off]);
      }
      *(short8*)&Bs[bn * 40 + kk] = v;
    }
    __syncthreads();

    const int arL = wm * 64 + (lane & 15);
    const int kq = (lane >> 4) << 3;
    const int bcL = wn * 64 + (lane & 15);
    short8 af[4], bfr[4];
#pragma unroll
    for (int mi = 0; mi < 4; ++mi) af[mi] = *(const short8*)&As[(arL + mi * 16) * 40 + kq];
#pragma unroll
    for (int ni = 0; ni < 4; ++ni) bfr[ni] = *(const short8*)&Bs[(bcL + ni * 16) * 40 + kq];
#pragma unroll
    for (int mi = 0; mi < 4; ++mi) {
#pragma unroll
      for (int ni = 0; ni < 4; ++ni) {
        acc[mi][ni] = __builtin_amdgcn_mfma_f32_16x16x32_bf16(
            __builtin_bit_cast(bf16x8, af[mi]), __builtin_bit_cast(bf16x8, bfr[ni]),
            acc[mi][ni], 0, 0, 0);
      }
    }
  }

  const int er = (lane >> 4) << 2;
  const int ec = lane & 15;
#pragma unroll
  for (int mi = 0; mi < 4; ++mi) {
#pragma unroll
    for (int ni = 0; ni < 4; ++ni) {
#pragma unroll
      for (int r = 0; r < 4; ++r) {
        float vv = fmaxf(acc[mi][ni][r], 0.f);
        const int row = row0 + wm * 64 + mi * 16 + er + r;
        const int col = n0 + wn * 64 + ni * 16 + ec;
        Aout[(size_t)row * N + col] = f2bf(vv);
      }
    }
  }
}

// final layer: z = h2 . (w0_3*wc_3[c]), sigmoid, scatter. 4 waves/block, 1 row/wave.
__global__ void layer3_kernel(const short* __restrict__ h2, const float* __restrict__ w03,
                              const float* __restrict__ wc3, const int* __restrict__ order,
                              const int* __restrict__ pstart, const int* __restrict__ meta,
                              float* __restrict__ out) {
  const int tid = threadIdx.x;
  const int lane = tid & 63;
  const int w = tid >> 6;
  const int r = blockIdx.x * 4 + w;
  if (r >= meta[1]) return;
  int c = 0;
#pragma unroll
  for (int i = 1; i < CLN; ++i) { if (r >= pstart[i]) c = i; }
  const short* hr = h2 + (size_t)r * 512;
  const int k0 = lane * 8;
  const short8 hv = *(const short8*)(hr + k0);
  const float* wcr = wc3 + c * 512;
  float part = 0.f;
#pragma unroll
  for (int j = 0; j < 8; ++j) part += bf2f(hv[j]) * w03[k0 + j] * wcr[k0 + j];
  for (int off = 32; off; off >>= 1) part += __shfl_down(part, off);
  if (lane == 0) out[order[r]] = 1.f / (1.f + expf(-part));
}

extern "C" void kernel_launch(void* const* d_in, const int* in_sizes, int n_in,
                              void* d_out, int out_size, void* d_ws, size_t ws_size,
                              hipStream_t stream) {
  const float* x = (const float*)d_in[0];
  const float* center = (const float*)d_in[1];
  const float* w0s[4]; const float* wcs[4];
  if (in_sizes[3] == 8 * in_sizes[2]) {  // dict order: w0_i, wc_i interleaved
    for (int i = 0; i < 4; ++i) { w0s[i] = (const float*)d_in[2 + 2 * i]; wcs[i] = (const float*)d_in[3 + 2 * i]; }
  } else {                               // signature order: w0_0..w0_3, wc_0..wc_3
    for (int i = 0; i < 4; ++i) { w0s[i] = (const float*)d_in[2 + i]; wcs[i] = (const float*)d_in[6 + i]; }
  }
  float* out = (float*)d_out;
  char* ws = (char*)d_ws;
  int* counts    = (int*)(ws + 0);      // 8
  int* pstart    = (int*)(ws + 128);    // 9
  int* meta      = (int*)(ws + 192);    // 2
  int* tile_c    = (int*)(ws + 256);    // 72
  int* tile_r    = (int*)(ws + 1024);   // 72
  int* blockcnt  = (int*)(ws + 1536);   // HB*CLN = 256
  int* blockbase = (int*)(ws + 2560);   // 256
  int* router    = (int*)(ws + 4096);   // 8192
  int* order     = (int*)(ws + 4096 + 4 * B_SZ);  // 9216, ends < 131072

  const size_t GW_BYTES = (size_t)CLN * 2048 * 1024 * 2;      // 32 MB (max layer)
  const size_t H0_BYTES = (size_t)PADMAX * 2048 * 2;          // 37.75 MB
  const size_t H1_BYTES = (size_t)PADMAX * 1024 * 2;          // 18.87 MB (>= XB 16.8 MB)
  const size_t NEED = 131072 + GW_BYTES + H0_BYTES + H1_BYTES;
  const bool fast = (ws_size >= NEED);

  // xb overlays h1: xb lives router->gemm0, h1 lives gemm1->gemm2 (disjoint)
  short* gw = (short*)(ws + 131072);
  short* h0 = (short*)(ws + 131072 + GW_BYTES);
  short* h1 = (short*)(ws + 131072 + GW_BYTES + H0_BYTES);
  short* xb = fast ? h1 : nullptr;

  router_kernel<<<B_SZ / 4, 256, 0, stream>>>(x, center, router, xb);
  hist_kernel<<<HB, 256, 0, stream>>>(router, blockcnt);
  scan_kernel<<<1, HB * CLN, 0, stream>>>(blockcnt, counts, pstart, meta, tile_c, tile_r, blockbase);
  scatter_kernel<<<HB, 256, 0, stream>>>(router, blockbase, order);
  fillpad_kernel<<<PADMAX / 256, 256, 0, stream>>>(counts, pstart, order);

  if (fast) {
    short* h2 = h0;  // h0 dead after gemm1

    gate_kernel<1024, 2048><<<dim3(32, 32, CLN), 256, 0, stream>>>(w0s[0], wcs[0], gw);
    gemm_async<1024, 2048, true><<<dim3(MAX_TILES, 16), 256, 0, stream>>>(
        xb, gw, h0, order, tile_c, tile_r, meta);
    gate_kernel<2048, 1024><<<dim3(64, 16, CLN), 256, 0, stream>>>(w0s[1], wcs[1], gw);
    gemm_async<2048, 1024, false><<<dim3(MAX_TILES, 8), 256, 0, stream>>>(
        h0, gw, h1, order, tile_c, tile_r, meta);
    gate_kernel<1024, 512><<<dim3(32, 8, CLN), 256, 0, stream>>>(w0s[2], wcs[2], gw);
    gemm_async<1024, 512, false><<<dim3(MAX_TILES, 4), 256, 0, stream>>>(
        h1, gw, h2, order, tile_c, tile_r, meta);
    layer3_kernel<<<(PADMAX + 3) / 4, 256, 0, stream>>>(h2, w0s[3], wcs[3], order, pstart, meta, out);
  } else {
    // fallback: round-1 fused-gating path (needs only ~66 MB)
    short* f0 = (short*)(ws + 131072);
    short* f1 = f0 + (size_t)PADMAX * 2048;
    short* f2 = f1 + (size_t)PADMAX * 1024;
    gemm_layer<1024, 2048, true><<<dim3(MAX_TILES, 16), 256, 0, stream>>>(
        x, nullptr, w0s[0], wcs[0], f0, order, tile_c, tile_r, meta);
    gemm_layer<2048, 1024, false><<<dim3(MAX_TILES, 8), 256, 0, stream>>>(
        nullptr, f0, w0s[1], wcs[1], f1, order, tile_c, tile_r, meta);
    gemm_layer<1024, 512, false><<<dim3(MAX_TILES, 4), 256, 0, stream>>>(
        nullptr, f1, w0s[2], wcs[2], f2, order, tile_c, tile_r, meta);
    layer3_kernel<<<(PADMAX + 3) / 4, 256, 0, stream>>>(f2, w0s[3], wcs[3], order, pstart, meta, out);
  }
}

// Round 5
// 404.361 us; speedup vs baseline: 1.7215x; 1.0055x over previous
//
#include <hip/hip_runtime.h>
#include <hip/hip_bf16.h>

#define B_SZ 8192
#define DIMS 1024
#define CLN 8
#define BM 128
#define PADMAX (B_SZ + CLN * BM)     // 9216
#define MAX_TILES (B_SZ / BM + CLN)  // 72

typedef __attribute__((ext_vector_type(8))) __bf16 bf16x8;
typedef __attribute__((ext_vector_type(8))) short short8;
typedef __attribute__((ext_vector_type(4))) short short4v;
typedef __attribute__((ext_vector_type(4))) float f32x4;

__device__ __forceinline__ short f2bf(float f) {
  __hip_bfloat16 h = __float2bfloat16(f);
  return __builtin_bit_cast(short, h);
}
__device__ __forceinline__ float bf2f(short s) {
  unsigned u = ((unsigned)(unsigned short)s) << 16;
  return __builtin_bit_cast(float, u);
}

// async 16B/lane global->LDS DMA. LDS dest is wave-uniform base; HW adds lane*16.
__device__ __forceinline__ void gl_lds16(const short* g, short* l) {
  __builtin_amdgcn_global_load_lds(
      (const __attribute__((address_space(1))) unsigned int*)(unsigned long long)(uintptr_t)g,
      (__attribute__((address_space(3))) unsigned int*)(unsigned long long)(uintptr_t)l,
      16, 0, 0);
}

// 4 waves/block, 1 sample/wave. float4 x loads; fused fp32->bf16 conversion into xb.
__global__ void router_kernel(const float* __restrict__ x, const float* __restrict__ center,
                              int* __restrict__ router, short* __restrict__ xb) {
  const int tid = threadIdx.x;
  const int lane = tid & 63;
  const int w = tid >> 6;
  const int s = blockIdx.x * 4 + w;
  const float4* xr = (const float4*)(x + (size_t)s * DIMS);
  float4 xv[4];
#pragma unroll
  for (int j = 0; j < 4; ++j) xv[j] = xr[j * 64 + lane];
  if (xb) {
    short* xbr = xb + (size_t)s * DIMS;
#pragma unroll
    for (int j = 0; j < 4; ++j) {
      short4v sv;
      sv[0] = f2bf(xv[j].x); sv[1] = f2bf(xv[j].y);
      sv[2] = f2bf(xv[j].z); sv[3] = f2bf(xv[j].w);
      *(short4v*)(xbr + j * 256 + lane * 4) = sv;
    }
  }
  float p[CLN];
#pragma unroll
  for (int c = 0; c < CLN; ++c) {
    const float4* cr = (const float4*)(center + (size_t)c * DIMS);
    float acc = 0.f;
#pragma unroll
    for (int j = 0; j < 4; ++j) {
      float4 cv = cr[j * 64 + lane];
      acc += xv[j].x * cv.x + xv[j].y * cv.y + xv[j].z * cv.z + xv[j].w * cv.w;
    }
    p[c] = acc;
  }
#pragma unroll
  for (int c = 0; c < CLN; ++c) {
#pragma unroll
    for (int m = 1; m < 64; m <<= 1) p[c] += __shfl_xor(p[c], m);
  }
  if (lane == 0) {
    int best = 0; float bv = p[0];
#pragma unroll
    for (int c = 1; c < CLN; ++c) { if (p[c] > bv) { bv = p[c]; best = c; } }
    router[s] = best;
  }
}

// mono-block counting sort: hist (wave ballots) + scan + scatter + fillpad.
// Replaces 4 kernels -> saves ~3 launch gaps. LDS atomics only; stability not
// needed (any within-cluster permutation computes identical outputs).
__global__ void sort_kernel(const int* __restrict__ router, int* __restrict__ counts,
                            int* __restrict__ pstart, int* __restrict__ meta,
                            int* __restrict__ tile_c, int* __restrict__ tile_r,
                            int* __restrict__ order) {
  __shared__ int bins[CLN];
  __shared__ int cur[CLN];
  __shared__ int ps_s[CLN + 1];
  const int t = threadIdx.x;
  const int lane = t & 63;
  if (t < CLN) bins[t] = 0;
  __syncthreads();
  int myc[8];
#pragma unroll
  for (int j = 0; j < 8; ++j) myc[j] = router[t + 1024 * j];
#pragma unroll
  for (int j = 0; j < 8; ++j) {
#pragma unroll
    for (int c = 0; c < CLN; ++c) {
      unsigned long long m = __ballot(myc[j] == c);
      if (lane == 0 && m) atomicAdd(&bins[c], __popcll(m));
    }
  }
  __syncthreads();
  if (t == 0) {
    int ps = 0, nt = 0;
    for (int c = 0; c < CLN; ++c) {
      const int tot = bins[c];
      counts[c] = tot; pstart[c] = ps; ps_s[c] = ps; cur[c] = 0;
      const int tiles = (tot + BM - 1) / BM;
      for (int i = 0; i < tiles; ++i) { tile_c[nt] = c; tile_r[nt] = ps + i * BM; ++nt; }
      ps += tiles * BM;
    }
    pstart[CLN] = ps; ps_s[CLN] = ps; meta[0] = nt; meta[1] = ps;
  }
  __syncthreads();
#pragma unroll
  for (int j = 0; j < 8; ++j) {
    const int s = t + 1024 * j;
    const int c = myc[j];
    int pos = 0;
#pragma unroll
    for (int cc = 0; cc < CLN; ++cc) {
      unsigned long long m = __ballot(c == cc);
      int b = 0;
      if (lane == 0 && m) b = atomicAdd(&cur[cc], __popcll(m));
      b = __shfl(b, 0);
      if (c == cc) pos = ps_s[cc] + b + __popcll(m & ((1ull << lane) - 1ull));
    }
    order[pos] = s;
  }
  __syncthreads();
  for (int p = t; p < PADMAX; p += 1024) {
#pragma unroll
    for (int c = 0; c < CLN; ++c) {
      if (p >= ps_s[c] && p < ps_s[c + 1]) {
        if (p - ps_s[c] >= bins[c]) order[p] = order[ps_s[c]];
        break;
      }
    }
  }
}

// -------- pre-gating: gwt[c][n][k] = bf16(w0[k][n] * wc[c][k][n]) --------
template <int K, int N>
__device__ __forceinline__ void gate_body(const float* __restrict__ w0,
                                          const float* __restrict__ wc,
                                          short* __restrict__ gwt, int bx, short* t) {
  constexpr int NK = K / 32, NN = N / 64;
  const int c = bx / (NK * NN);
  const int rem = bx % (NK * NN);
  const int k0 = (rem % NK) * 32;
  const int n0 = (rem / NK) * 64;
  const int tid = threadIdx.x;
  const int lk = tid >> 4;
  const int ln = (tid & 15) * 4;
  const float* w0p = w0 + (size_t)k0 * N + n0;
  const float* wcp = wc + (size_t)c * K * N + (size_t)k0 * N + n0;
#pragma unroll
  for (int i = 0; i < 2; ++i) {
    const int k = lk + i * 16;
    float4 a = *(const float4*)(w0p + (size_t)k * N + ln);
    float4 b = *(const float4*)(wcp + (size_t)k * N + ln);
    short* d = &t[k * 65 + ln];
    d[0] = f2bf(a.x * b.x); d[1] = f2bf(a.y * b.y);
    d[2] = f2bf(a.z * b.z); d[3] = f2bf(a.w * b.w);
  }
  __syncthreads();
  const int wn = tid >> 2;
  const int wk = (tid & 3) * 8;
  short8 v;
#pragma unroll
  for (int j = 0; j < 8; ++j) v[j] = t[(wk + j) * 65 + wn];
  *(short8*)(gwt + ((size_t)c * N + n0 + wn) * K + k0 + wk) = v;
}

// one launch covers all three layers (tier A: separate gw buffers)
__global__ void gate_all(const float* __restrict__ w00, const float* __restrict__ wc0, short* g0,
                         const float* __restrict__ w01, const float* __restrict__ wc1, short* g1,
                         const float* __restrict__ w02, const float* __restrict__ wc2, short* g2) {
  __shared__ short t[32 * 65];
  const int bx = blockIdx.x;
  if (bx < 8192)       gate_body<1024, 2048>(w00, wc0, g0, bx, t);
  else if (bx < 16384) gate_body<2048, 1024>(w01, wc1, g1, bx - 8192, t);
  else                 gate_body<1024, 512>(w02, wc2, g2, bx - 16384, t);
}

// tier-B single-layer gate
template <int K, int N>
__global__ void gate_kernel(const float* __restrict__ w0, const float* __restrict__ wc,
                            short* __restrict__ gwt) {
  __shared__ short t[32 * 65];
  gate_body<K, N>(w0, wc, gwt, blockIdx.x, t);
}

// -------- GEMM: BK=64 via twin BK=32 panels, global_load_lds(16B), bf16 --------
// 128x128 tile, 4 waves (2x2 of 64x64), mfma_f32_16x16x32_bf16.
// Flat 1-D grid, n0 fastest: B-sharers (stride NT = 0 mod 8) pin to one XCD,
// A-sharers spread across XCDs -> L2 locality (round-4 FETCH was 3x compulsory).
template <int K, int N, bool GATHER>
__global__ void gemm_async(const short* __restrict__ Abase, const short* __restrict__ gwt,
                           short* __restrict__ Aout, const int* __restrict__ order,
                           const int* __restrict__ tile_c, const int* __restrict__ tile_r,
                           const int* __restrict__ meta) {
  constexpr int NT = N / 128;
  const int bt = blockIdx.x / NT;
  if (bt >= meta[0]) return;
  const int n0 = (blockIdx.x % NT) * 128;
  const int cl = tile_c[bt];
  const int row0 = tile_r[bt];

  __shared__ __align__(16) short As0[128 * 32];
  __shared__ __align__(16) short As1[128 * 32];
  __shared__ __align__(16) short Bs0[128 * 32];
  __shared__ __align__(16) short Bs1[128 * 32];

  const int tid = threadIdx.x;
  const int lane = tid & 63;
  const int w = tid >> 6;
  const int wm = w >> 1;
  const int wn = w & 1;

  // staging geometry (per 1KB instr): 16 rows x 64B; lane i -> row i/4, k-seg (i%4)*8
  const int lrow = lane >> 2;
  const int kofs = (lane & 3) << 3;
  const short* ga0;
  const short* ga1;
  if (GATHER) {
    ga0 = Abase + (size_t)order[row0 + w * 16 + lrow] * K + kofs;
    ga1 = Abase + (size_t)order[row0 + 64 + w * 16 + lrow] * K + kofs;
  } else {
    ga0 = Abase + (size_t)(row0 + w * 16 + lrow) * K + kofs;
    ga1 = ga0 + (size_t)64 * K;
  }
  const short* gb0 = gwt + ((size_t)cl * N + n0 + w * 16 + lrow) * K + kofs;
  const short* gb1 = gb0 + (size_t)64 * K;
  short* lo = (short*)((char*)nullptr);  // silence unused warnings pattern
  (void)lo;
  short* lA0a = &As0[w * 16 * 32];
  short* lA0b = &As0[(64 + w * 16) * 32];
  short* lA1a = &As1[w * 16 * 32];
  short* lA1b = &As1[(64 + w * 16) * 32];
  short* lB0a = &Bs0[w * 16 * 32];
  short* lB0b = &Bs0[(64 + w * 16) * 32];
  short* lB1a = &Bs1[w * 16 * 32];
  short* lB1b = &Bs1[(64 + w * 16) * 32];

  f32x4 acc[4][4] = {};
  const int arL = wm * 64 + (lane & 15);
  const int bcL = wn * 64 + (lane & 15);
  const int kq = (lane >> 4) << 3;

  for (int kb = 0; kb < K; kb += 64) {
    __syncthreads();
    gl_lds16(ga0 + kb, lA0a);
    gl_lds16(ga1 + kb, lA0b);
    gl_lds16(ga0 + kb + 32, lA1a);
    gl_lds16(ga1 + kb + 32, lA1b);
    gl_lds16(gb0 + kb, lB0a);
    gl_lds16(gb1 + kb, lB0b);
    gl_lds16(gb0 + kb + 32, lB1a);
    gl_lds16(gb1 + kb + 32, lB1b);
    __syncthreads();

#pragma unroll
    for (int h = 0; h < 2; ++h) {
      const short* Ap = h ? As1 : As0;
      const short* Bp = h ? Bs1 : Bs0;
      short8 af[4], bfr[4];
#pragma unroll
      for (int mi = 0; mi < 4; ++mi) af[mi] = *(const short8*)&Ap[(arL + mi * 16) * 32 + kq];
#pragma unroll
      for (int ni = 0; ni < 4; ++ni) bfr[ni] = *(const short8*)&Bp[(bcL + ni * 16) * 32 + kq];
#pragma unroll
      for (int mi = 0; mi < 4; ++mi) {
#pragma unroll
        for (int ni = 0; ni < 4; ++ni) {
          acc[mi][ni] = __builtin_amdgcn_mfma_f32_16x16x32_bf16(
              __builtin_bit_cast(bf16x8, af[mi]), __builtin_bit_cast(bf16x8, bfr[ni]),
              acc[mi][ni], 0, 0, 0);
        }
      }
    }
  }

  // epilogue: relu + bf16 store. C/D layout: col=lane&15, row=(lane>>4)*4+reg
  const int er = (lane >> 4) << 2;
  const int ec = lane & 15;
#pragma unroll
  for (int mi = 0; mi < 4; ++mi) {
#pragma unroll
    for (int ni = 0; ni < 4; ++ni) {
#pragma unroll
      for (int r = 0; r < 4; ++r) {
        float vv = fmaxf(acc[mi][ni][r], 0.f);
        const int row = row0 + wm * 64 + mi * 16 + er + r;
        const int col = n0 + wn * 64 + ni * 16 + ec;
        Aout[(size_t)row * N + col] = f2bf(vv);
      }
    }
  }
}

// -------- fallback GEMM (round-1): gating fused in staging, fp32 weights --------
template <int K, int N, bool GATHER>
__global__ void gemm_layer(const float* __restrict__ Xf, const short* __restrict__ Ain,
                           const float* __restrict__ w0, const float* __restrict__ wc,
                           short* __restrict__ Aout,
                           const int* __restrict__ order,
                           const int* __restrict__ tile_c, const int* __restrict__ tile_r,
                           const int* __restrict__ meta) {
  const int bt = blockIdx.x;
  if (bt >= meta[0]) return;
  const int cl = tile_c[bt];
  const int row0 = tile_r[bt];
  const int n0 = blockIdx.y * 128;

  __shared__ __align__(16) short As[128 * 40];
  __shared__ __align__(16) short Bs[128 * 40];

  const int tid = threadIdx.x;
  const int lane = tid & 63;
  const int wm = (tid >> 6) >> 1;
  const int wn = (tid >> 6) & 1;

  f32x4 acc[4][4] = {};

  const int arow = tid >> 2;
  const int akseg = (tid & 3) << 3;
  const int bn = tid & 127;
  const int bkq = (tid >> 7) << 3;

  const float* xr0 = nullptr; const float* xr1 = nullptr;
  const short* ar0 = nullptr; const short* ar1 = nullptr;
  if (GATHER) {
    xr0 = Xf + (size_t)order[row0 + arow] * K + akseg;
    xr1 = Xf + (size_t)order[row0 + arow + 64] * K + akseg;
  } else {
    ar0 = Ain + (size_t)(row0 + arow) * K + akseg;
    ar1 = Ain + (size_t)(row0 + arow + 64) * K + akseg;
  }
  const float* w0p = w0 + n0 + bn;
  const float* wcp = wc + (size_t)cl * K * N + n0 + bn;

  for (int kb = 0; kb < K; kb += 32) {
    __syncthreads();
    if (GATHER) {
      float4 a = *(const float4*)(xr0 + kb);
      float4 b = *(const float4*)(xr0 + kb + 4);
      short8 v;
      v[0] = f2bf(a.x); v[1] = f2bf(a.y); v[2] = f2bf(a.z); v[3] = f2bf(a.w);
      v[4] = f2bf(b.x); v[5] = f2bf(b.y); v[6] = f2bf(b.z); v[7] = f2bf(b.w);
      *(short8*)&As[arow * 40 + akseg] = v;
      a = *(const float4*)(xr1 + kb);
      b = *(const float4*)(xr1 + kb + 4);
      v[0] = f2bf(a.x); v[1] = f2bf(a.y); v[2] = f2bf(a.z); v[3] = f2bf(a.w);
      v[4] = f2bf(b.x); v[5] = f2bf(b.y); v[6] = f2bf(b.z); v[7] = f2bf(b.w);
      *(short8*)&As[(arow + 64) * 40 + akseg] = v;
    } else {
      *(short8*)&As[arow * 40 + akseg] = *(const short8*)(ar0 + kb);
      *(short8*)&As[(arow + 64) * 40 + akseg] = *(const short8*)(ar1 + kb);
    }
#pragma unroll
    for (int half = 0; half < 2; ++half) {
      const int kk = bkq + half * 16;
      short8 v;
#pragma unroll
      for (int j = 0; j < 8; ++j) {
        const size_t off = (size_t)(kb + kk + j) * N;
        v[j] = f2bf(w0p[off] * wcp[off]);
      }
      *(short8*)&Bs[bn * 40 + kk] = v;
    }
    __syncthreads();

    const int arL = wm * 64 + (lane & 15);
    const int kq = (lane >> 4) << 3;
    const int bcL = wn * 64 + (lane & 15);
    short8 af[4], bfr[4];
#pragma unroll
    for (int mi = 0; mi < 4; ++mi) af[mi] = *(const short8*)&As[(arL + mi * 16) * 40 + kq];
#pragma unroll
    for (int ni = 0; ni < 4; ++ni) bfr[ni] = *(const short8*)&Bs[(bcL + ni * 16) * 40 + kq];
#pragma unroll
    for (int mi = 0; mi < 4; ++mi) {
#pragma unroll
      for (int ni = 0; ni < 4; ++ni) {
        acc[mi][ni] = __builtin_amdgcn_mfma_f32_16x16x32_bf16(
            __builtin_bit_cast(bf16x8, af[mi]), __builtin_bit_cast(bf16x8, bfr[ni]),
            acc[mi][ni], 0, 0, 0);
      }
    }
  }

  const int er = (lane >> 4) << 2;
  const int ec = lane & 15;
#pragma unroll
  for (int mi = 0; mi < 4; ++mi) {
#pragma unroll
    for (int ni = 0; ni < 4; ++ni) {
#pragma unroll
      for (int r = 0; r < 4; ++r) {
        float vv = fmaxf(acc[mi][ni][r], 0.f);
        const int row = row0 + wm * 64 + mi * 16 + er + r;
        const int col = n0 + wn * 64 + ni * 16 + ec;
        Aout[(size_t)row * N + col] = f2bf(vv);
      }
    }
  }
}

// final layer: z = h2 . (w0_3*wc_3[c]), sigmoid, scatter. 4 waves/block, 1 row/wave.
__global__ void layer3_kernel(const short* __restrict__ h2, const float* __restrict__ w03,
                              const float* __restrict__ wc3, const int* __restrict__ order,
                              const int* __restrict__ pstart, const int* __restrict__ meta,
                              float* __restrict__ out) {
  const int tid = threadIdx.x;
  const int lane = tid & 63;
  const int w = tid >> 6;
  const int r = blockIdx.x * 4 + w;
  if (r >= meta[1]) return;
  int c = 0;
#pragma unroll
  for (int i = 1; i < CLN; ++i) { if (r >= pstart[i]) c = i; }
  const short* hr = h2 + (size_t)r * 512;
  const int k0 = lane * 8;
  const short8 hv = *(const short8*)(hr + k0);
  const float* wcr = wc3 + c * 512;
  float part = 0.f;
#pragma unroll
  for (int j = 0; j < 8; ++j) part += bf2f(hv[j]) * w03[k0 + j] * wcr[k0 + j];
  for (int off = 32; off; off >>= 1) part += __shfl_down(part, off);
  if (lane == 0) out[order[r]] = 1.f / (1.f + expf(-part));
}

extern "C" void kernel_launch(void* const* d_in, const int* in_sizes, int n_in,
                              void* d_out, int out_size, void* d_ws, size_t ws_size,
                              hipStream_t stream) {
  const float* x = (const float*)d_in[0];
  const float* center = (const float*)d_in[1];
  const float* w0s[4]; const float* wcs[4];
  if (in_sizes[3] == 8 * in_sizes[2]) {  // dict order: w0_i, wc_i interleaved
    for (int i = 0; i < 4; ++i) { w0s[i] = (const float*)d_in[2 + 2 * i]; wcs[i] = (const float*)d_in[3 + 2 * i]; }
  } else {                               // signature order: w0_0..w0_3, wc_0..wc_3
    for (int i = 0; i < 4; ++i) { w0s[i] = (const float*)d_in[2 + i]; wcs[i] = (const float*)d_in[6 + i]; }
  }
  float* out = (float*)d_out;
  char* ws = (char*)d_ws;
  int* counts = (int*)(ws + 0);      // 8
  int* pstart = (int*)(ws + 128);    // 9
  int* meta   = (int*)(ws + 192);    // 2
  int* tile_c = (int*)(ws + 256);    // 72
  int* tile_r = (int*)(ws + 1024);   // 72
  int* router = (int*)(ws + 4096);   // 8192
  int* order  = (int*)(ws + 4096 + 4 * B_SZ);  // 9216, ends < 131072

  const size_t GW0 = (size_t)CLN * 1024 * 2048 * 2;   // 33.55 MB
  const size_t GW1 = (size_t)CLN * 2048 * 1024 * 2;   // 33.55 MB
  const size_t GW2 = (size_t)CLN * 1024 * 512 * 2;    // 8.39 MB
  const size_t H0B = (size_t)PADMAX * 2048 * 2;       // 37.75 MB
  const size_t H1B = (size_t)PADMAX * 1024 * 2;       // 18.87 MB (>= xb 16.8 MB)
  const size_t NEED_A = 131072 + GW0 + GW1 + GW2 + H0B + H1B;  // ~132.3 MB
  const size_t NEED_B = 131072 + GW1 + H0B + H1B;              // ~90.3 MB (proven fits)
  const int tier = (ws_size >= NEED_A) ? 0 : (ws_size >= NEED_B) ? 1 : 2;

  if (tier == 0) {
    short* gw0 = (short*)(ws + 131072);
    short* gw1 = (short*)(ws + 131072 + GW0);
    short* gw2 = (short*)(ws + 131072 + GW0 + GW1);
    short* h0  = (short*)(ws + 131072 + GW0 + GW1 + GW2);
    short* h1  = (short*)(ws + 131072 + GW0 + GW1 + GW2 + H0B);
    short* xb  = h1;   // disjoint lifetimes: xb router->gemm0, h1 gemm1->gemm2
    short* h2  = h0;   // h0 dead after gemm1

    router_kernel<<<B_SZ / 4, 256, 0, stream>>>(x, center, router, xb);
    sort_kernel<<<1, 1024, 0, stream>>>(router, counts, pstart, meta, tile_c, tile_r, order);
    gate_all<<<18432, 256, 0, stream>>>(w0s[0], wcs[0], gw0, w0s[1], wcs[1], gw1,
                                        w0s[2], wcs[2], gw2);
    gemm_async<1024, 2048, true><<<MAX_TILES * 16, 256, 0, stream>>>(
        xb, gw0, h0, order, tile_c, tile_r, meta);
    gemm_async<2048, 1024, false><<<MAX_TILES * 8, 256, 0, stream>>>(
        h0, gw1, h1, order, tile_c, tile_r, meta);
    gemm_async<1024, 512, false><<<MAX_TILES * 4, 256, 0, stream>>>(
        h1, gw2, h2, order, tile_c, tile_r, meta);
    layer3_kernel<<<(PADMAX + 3) / 4, 256, 0, stream>>>(h2, w0s[3], wcs[3], order, pstart, meta, out);
  } else if (tier == 1) {
    short* gw = (short*)(ws + 131072);
    short* h0 = (short*)(ws + 131072 + GW1);
    short* h1 = (short*)(ws + 131072 + GW1 + H0B);
    short* xb = h1;
    short* h2 = h0;

    router_kernel<<<B_SZ / 4, 256, 0, stream>>>(x, center, router, xb);
    sort_kernel<<<1, 1024, 0, stream>>>(router, counts, pstart, meta, tile_c, tile_r, order);
    gate_kernel<1024, 2048><<<8192, 256, 0, stream>>>(w0s[0], wcs[0], gw);
    gemm_async<1024, 2048, true><<<MAX_TILES * 16, 256, 0, stream>>>(
        xb, gw, h0, order, tile_c, tile_r, meta);
    gate_kernel<2048, 1024><<<8192, 256, 0, stream>>>(w0s[1], wcs[1], gw);
    gemm_async<2048, 1024, false><<<MAX_TILES * 8, 256, 0, stream>>>(
        h0, gw, h1, order, tile_c, tile_r, meta);
    gate_kernel<1024, 512><<<2048, 256, 0, stream>>>(w0s[2], wcs[2], gw);
    gemm_async<1024, 512, false><<<MAX_TILES * 4, 256, 0, stream>>>(
        h1, gw, h2, order, tile_c, tile_r, meta);
    layer3_kernel<<<(PADMAX + 3) / 4, 256, 0, stream>>>(h2, w0s[3], wcs[3], order, pstart, meta, out);
  } else {
    short* f0 = (short*)(ws + 131072);
    short* f1 = f0 + (size_t)PADMAX * 2048;
    short* f2 = f1 + (size_t)PADMAX * 1024;
    router_kernel<<<B_SZ / 4, 256, 0, stream>>>(x, center, router, nullptr);
    sort_kernel<<<1, 1024, 0, stream>>>(router, counts, pstart, meta, tile_c, tile_r, order);
    gemm_layer<1024, 2048, true><<<dim3(MAX_TILES, 16), 256, 0, stream>>>(
        x, nullptr, w0s[0], wcs[0], f0, order, tile_c, tile_r, meta);
    gemm_layer<2048, 1024, false><<<dim3(MAX_TILES, 8), 256, 0, stream>>>(
        nullptr, f0, w0s[1], wcs[1], f1, order, tile_c, tile_r, meta);
    gemm_layer<1024, 512, false><<<dim3(MAX_TILES, 4), 256, 0, stream>>>(
        nullptr, f1, w0s[2], wcs[2], f2, order, tile_c, tile_r, meta);
    layer3_kernel<<<(PADMAX + 3) / 4, 256, 0, stream>>>(f2, w0s[3], wcs[3], order, pstart, meta, out);
  }
}

// Round 6
// 396.189 us; speedup vs baseline: 1.7570x; 1.0206x over previous
//
#include <hip/hip_runtime.h>
#include <hip/hip_bf16.h>

#define B_SZ 8192
#define DIMS 1024
#define CLN 8
#define BM 128
#define PADMAX (B_SZ + CLN * BM)     // 9216
#define MAX_TILES (B_SZ / BM + CLN)  // 72

typedef __attribute__((ext_vector_type(8))) __bf16 bf16x8;
typedef __attribute__((ext_vector_type(8))) short short8;
typedef __attribute__((ext_vector_type(4))) short short4v;
typedef __attribute__((ext_vector_type(4))) float f32x4;

__device__ __forceinline__ short f2bf(float f) {
  __hip_bfloat16 h = __float2bfloat16(f);
  return __builtin_bit_cast(short, h);
}
__device__ __forceinline__ float bf2f(short s) {
  unsigned u = ((unsigned)(unsigned short)s) << 16;
  return __builtin_bit_cast(float, u);
}

// async 16B/lane global->LDS DMA. LDS dest is wave-uniform base; HW adds lane*16.
__device__ __forceinline__ void gl_lds16(const short* g, short* l) {
  __builtin_amdgcn_global_load_lds(
      (const __attribute__((address_space(1))) unsigned int*)(unsigned long long)(uintptr_t)g,
      (__attribute__((address_space(3))) unsigned int*)(unsigned long long)(uintptr_t)l,
      16, 0, 0);
}

// ---- router body: 4 waves/block, 1 sample/wave, fused fp32->bf16 of x ----
__device__ __forceinline__ void router_body(const float* __restrict__ x,
                                            const float* __restrict__ center,
                                            int* __restrict__ router, short* __restrict__ xb,
                                            int bx) {
  const int tid = threadIdx.x;
  const int lane = tid & 63;
  const int w = tid >> 6;
  const int s = bx * 4 + w;
  const float4* xr = (const float4*)(x + (size_t)s * DIMS);
  float4 xv[4];
#pragma unroll
  for (int j = 0; j < 4; ++j) xv[j] = xr[j * 64 + lane];
  if (xb) {
    short* xbr = xb + (size_t)s * DIMS;
#pragma unroll
    for (int j = 0; j < 4; ++j) {
      short4v sv;
      sv[0] = f2bf(xv[j].x); sv[1] = f2bf(xv[j].y);
      sv[2] = f2bf(xv[j].z); sv[3] = f2bf(xv[j].w);
      *(short4v*)(xbr + j * 256 + lane * 4) = sv;
    }
  }
  float p[CLN];
#pragma unroll
  for (int c = 0; c < CLN; ++c) {
    const float4* cr = (const float4*)(center + (size_t)c * DIMS);
    float acc = 0.f;
#pragma unroll
    for (int j = 0; j < 4; ++j) {
      float4 cv = cr[j * 64 + lane];
      acc += xv[j].x * cv.x + xv[j].y * cv.y + xv[j].z * cv.z + xv[j].w * cv.w;
    }
    p[c] = acc;
  }
#pragma unroll
  for (int c = 0; c < CLN; ++c) {
#pragma unroll
    for (int m = 1; m < 64; m <<= 1) p[c] += __shfl_xor(p[c], m);
  }
  if (lane == 0) {
    int best = 0; float bv = p[0];
#pragma unroll
    for (int c = 1; c < CLN; ++c) { if (p[c] > bv) { bv = p[c]; best = c; } }
    router[s] = best;
  }
}

// ---- wide-LDS gate body: gwt[c][n][k] = bf16(w0[k][n]*wc[c][k][n]) ----
// 64k x 64n tile. Phase1: coalesced fp32 reads, pack k-quads -> ds_write_b64.
// Phase2: 4x ds_read_b64 (2-way alias = free) -> 2x global dwordx4.
// Round-5 lesson: the old 32x64 gate was LDS-width-bound (8x ds_read_u16/thread).
#define GPAD 68  // shorts per LDS row (136 B: odd dword stride, b64-aligned)
template <int K, int N>
__device__ __forceinline__ void gate_body(const float* __restrict__ w0,
                                          const float* __restrict__ wc,
                                          short* __restrict__ gwt, int bx, short* lds) {
  constexpr int KB = K / 64, NB = N / 64;
  const int c = bx / (KB * NB);
  const int rem = bx % (KB * NB);
  const int k0 = (rem % KB) * 64;
  const int n0 = (rem / KB) * 64;
  const int tid = threadIdx.x;
  // phase 1: thread (i = tid&15 -> n4 = 4i, q = tid>>4 -> kquad) loads 4 rows x float4
  const int n4 = (tid & 15) * 4;
  const int q = tid >> 4;
  const float* w0p = w0 + (size_t)(k0 + q * 4) * N + n0 + n4;
  const float* wcp = wc + ((size_t)c * K + k0 + q * 4) * N + n0 + n4;
  float4 a[4], b[4];
#pragma unroll
  for (int j = 0; j < 4; ++j) {
    a[j] = *(const float4*)(w0p + (size_t)j * N);
    b[j] = *(const float4*)(wcp + (size_t)j * N);
  }
#pragma unroll
  for (int jj = 0; jj < 4; ++jj) {
    const float* af0 = (const float*)&a[0]; const float* bf0 = (const float*)&b[0];
    const float* af1 = (const float*)&a[1]; const float* bf1 = (const float*)&b[1];
    const float* af2 = (const float*)&a[2]; const float* bf2 = (const float*)&b[2];
    const float* af3 = (const float*)&a[3]; const float* bf3 = (const float*)&b[3];
    short4v sv;
    sv[0] = f2bf(af0[jj] * bf0[jj]);
    sv[1] = f2bf(af1[jj] * bf1[jj]);
    sv[2] = f2bf(af2[jj] * bf2[jj]);
    sv[3] = f2bf(af3[jj] * bf3[jj]);
    *(short4v*)&lds[(n4 + jj) * GPAD + q * 4] = sv;
  }
  __syncthreads();
  // phase 2: thread (n = tid>>2, qg = tid&3) reads 16 shorts, stores 32 B
  const int n = tid >> 2;
  const int qg = tid & 3;
  const short* src = &lds[n * GPAD + qg * 16];
  short4v r0 = *(const short4v*)(src + 0);
  short4v r1 = *(const short4v*)(src + 4);
  short4v r2 = *(const short4v*)(src + 8);
  short4v r3 = *(const short4v*)(src + 12);
  short8 o0, o1;
  o0[0]=r0[0]; o0[1]=r0[1]; o0[2]=r0[2]; o0[3]=r0[3];
  o0[4]=r1[0]; o0[5]=r1[1]; o0[6]=r1[2]; o0[7]=r1[3];
  o1[0]=r2[0]; o1[1]=r2[1]; o1[2]=r2[2]; o1[3]=r2[3];
  o1[4]=r3[0]; o1[5]=r3[1]; o1[6]=r3[2]; o1[7]=r3[3];
  short* dst = gwt + ((size_t)c * N + n0 + n) * K + k0 + qg * 16;
  *(short8*)dst = o0;
  *(short8*)(dst + 8) = o1;
}

// ---- fused prep: router blocks first, then all three gate layers ----
// L0: 16*32*8=4096, L1: 32*16*8=4096, L2: 16*8*8=1024 gate blocks.
__global__ void prep_kernel(const float* __restrict__ x, const float* __restrict__ center,
                            int* __restrict__ router, short* __restrict__ xb,
                            const float* w00, const float* wc0, short* g0,
                            const float* w01, const float* wc1, short* g1,
                            const float* w02, const float* wc2, short* g2) {
  __shared__ short lds[64 * GPAD];
  const int bx = blockIdx.x;
  if (bx < 2048) { router_body(x, center, router, xb, bx); return; }
  const int gx = bx - 2048;
  if (gx < 4096)       gate_body<1024, 2048>(w00, wc0, g0, gx, lds);
  else if (gx < 8192)  gate_body<2048, 1024>(w01, wc1, g1, gx - 4096, lds);
  else                 gate_body<1024, 512>(w02, wc2, g2, gx - 8192, lds);
}

// tier-1 single-layer gate
template <int K, int N>
__global__ void gate1_kernel(const float* __restrict__ w0, const float* __restrict__ wc,
                             short* __restrict__ gwt) {
  __shared__ short lds[64 * GPAD];
  gate_body<K, N>(w0, wc, gwt, blockIdx.x, lds);
}

// ---- mono-block counting sort + zero z ----
__global__ void sort_kernel(const int* __restrict__ router, int* __restrict__ counts,
                            int* __restrict__ pstart, int* __restrict__ meta,
                            int* __restrict__ tile_c, int* __restrict__ tile_r,
                            int* __restrict__ order, float* __restrict__ z) {
  __shared__ int bins[CLN];
  __shared__ int cur[CLN];
  __shared__ int ps_s[CLN + 1];
  const int t = threadIdx.x;
  const int lane = t & 63;
  for (int p = t; p < PADMAX; p += 1024) z[p] = 0.f;   // gemm2 dot-accumulator
  if (t < CLN) bins[t] = 0;
  __syncthreads();
  int myc[8];
#pragma unroll
  for (int j = 0; j < 8; ++j) myc[j] = router[t + 1024 * j];
#pragma unroll
  for (int j = 0; j < 8; ++j) {
#pragma unroll
    for (int c = 0; c < CLN; ++c) {
      unsigned long long m = __ballot(myc[j] == c);
      if (lane == 0 && m) atomicAdd(&bins[c], __popcll(m));
    }
  }
  __syncthreads();
  if (t == 0) {
    int ps = 0, nt = 0;
    for (int c = 0; c < CLN; ++c) {
      const int tot = bins[c];
      counts[c] = tot; pstart[c] = ps; ps_s[c] = ps; cur[c] = 0;
      const int tiles = (tot + BM - 1) / BM;
      for (int i = 0; i < tiles; ++i) { tile_c[nt] = c; tile_r[nt] = ps + i * BM; ++nt; }
      ps += tiles * BM;
    }
    pstart[CLN] = ps; ps_s[CLN] = ps; meta[0] = nt; meta[1] = ps;
  }
  __syncthreads();
#pragma unroll
  for (int j = 0; j < 8; ++j) {
    const int s = t + 1024 * j;
    const int c = myc[j];
    int pos = 0;
#pragma unroll
    for (int cc = 0; cc < CLN; ++cc) {
      unsigned long long m = __ballot(c == cc);
      int b = 0;
      if (lane == 0 && m) b = atomicAdd(&cur[cc], __popcll(m));
      b = __shfl(b, 0);
      if (c == cc) pos = ps_s[cc] + b + __popcll(m & ((1ull << lane) - 1ull));
    }
    order[pos] = s;
  }
  __syncthreads();
  for (int p = t; p < PADMAX; p += 1024) {
#pragma unroll
    for (int c = 0; c < CLN; ++c) {
      if (p >= ps_s[c] && p < ps_s[c + 1]) {
        if (p - ps_s[c] >= bins[c]) order[p] = order[ps_s[c]];
        break;
      }
    }
  }
}

// -------- GEMM: BK=32 (round-4-measured), global_load_lds(16B), bf16 --------
// 128x128 tile, 4 waves (2x2 of 64x64), mfma_f32_16x16x32_bf16.
// 1-D grid, n0 fastest: B-slice sharers (stride NT = 0 mod 8) pin to one XCD.
// FUSE_DOT (layer 2): epilogue computes gated w3 dot per row + atomicAdd to z
// instead of writing h2 (saves 19 MB write + re-read + a kernel).
template <int K, int N, bool GATHER, bool FUSE_DOT>
__global__ void gemm_async(const short* __restrict__ Abase, const short* __restrict__ gwt,
                           short* __restrict__ Aout, const int* __restrict__ order,
                           const int* __restrict__ tile_c, const int* __restrict__ tile_r,
                           const int* __restrict__ meta,
                           const float* __restrict__ w03, const float* __restrict__ wc3,
                           float* __restrict__ z) {
  constexpr int NT = N / 128;
  const int bt = blockIdx.x / NT;
  if (bt >= meta[0]) return;
  const int n0 = (blockIdx.x % NT) * 128;
  const int cl = tile_c[bt];
  const int row0 = tile_r[bt];

  __shared__ __align__(16) short As[128 * 32];
  __shared__ __align__(16) short Bs[128 * 32];  // Bs[n][k]

  const int tid = threadIdx.x;
  const int lane = tid & 63;
  const int w = tid >> 6;
  const int wm = w >> 1;
  const int wn = w & 1;

  const int lrow = lane >> 2;
  const int kofs = (lane & 3) << 3;
  const short* ga0;
  const short* ga1;
  if (GATHER) {
    ga0 = Abase + (size_t)order[row0 + w * 16 + lrow] * K + kofs;
    ga1 = Abase + (size_t)order[row0 + 64 + w * 16 + lrow] * K + kofs;
  } else {
    ga0 = Abase + (size_t)(row0 + w * 16 + lrow) * K + kofs;
    ga1 = ga0 + (size_t)64 * K;
  }
  const short* gb0 = gwt + ((size_t)cl * N + n0 + w * 16 + lrow) * K + kofs;
  const short* gb1 = gb0 + (size_t)64 * K;
  short* lA0 = &As[w * 16 * 32];
  short* lA1 = &As[(64 + w * 16) * 32];
  short* lB0 = &Bs[w * 16 * 32];
  short* lB1 = &Bs[(64 + w * 16) * 32];

  f32x4 acc[4][4] = {};
  const int arL = wm * 64 + (lane & 15);
  const int bcL = wn * 64 + (lane & 15);
  const int kq = (lane >> 4) << 3;

  for (int kb = 0; kb < K; kb += 32) {
    __syncthreads();
    gl_lds16(ga0 + kb, lA0);
    gl_lds16(ga1 + kb, lA1);
    gl_lds16(gb0 + kb, lB0);
    gl_lds16(gb1 + kb, lB1);
    __syncthreads();

    short8 af[4], bfr[4];
#pragma unroll
    for (int mi = 0; mi < 4; ++mi) af[mi] = *(const short8*)&As[(arL + mi * 16) * 32 + kq];
#pragma unroll
    for (int ni = 0; ni < 4; ++ni) bfr[ni] = *(const short8*)&Bs[(bcL + ni * 16) * 32 + kq];
#pragma unroll
    for (int mi = 0; mi < 4; ++mi) {
#pragma unroll
      for (int ni = 0; ni < 4; ++ni) {
        acc[mi][ni] = __builtin_amdgcn_mfma_f32_16x16x32_bf16(
            __builtin_bit_cast(bf16x8, af[mi]), __builtin_bit_cast(bf16x8, bfr[ni]),
            acc[mi][ni], 0, 0, 0);
      }
    }
  }

  // C/D layout: col=lane&15, row=(lane>>4)*4+reg
  const int er = (lane >> 4) << 2;
  const int ec = lane & 15;
  if constexpr (FUSE_DOT) {
    float g[4];
#pragma unroll
    for (int ni = 0; ni < 4; ++ni) {
      const int col = n0 + wn * 64 + ni * 16 + ec;
      g[ni] = w03[col] * wc3[cl * N + col];
    }
#pragma unroll
    for (int mi = 0; mi < 4; ++mi) {
#pragma unroll
      for (int r = 0; r < 4; ++r) {
        float v = 0.f;
#pragma unroll
        for (int ni = 0; ni < 4; ++ni) v += fmaxf(acc[mi][ni][r], 0.f) * g[ni];
#pragma unroll
        for (int m = 1; m < 16; m <<= 1) v += __shfl_xor(v, m);
        if ((lane & 15) == 0)
          atomicAdd(&z[row0 + wm * 64 + mi * 16 + er + r], v);
      }
    }
  } else {
#pragma unroll
    for (int mi = 0; mi < 4; ++mi) {
#pragma unroll
      for (int ni = 0; ni < 4; ++ni) {
#pragma unroll
        for (int r = 0; r < 4; ++r) {
          float vv = fmaxf(acc[mi][ni][r], 0.f);
          const int row = row0 + wm * 64 + mi * 16 + er + r;
          const int col = n0 + wn * 64 + ni * 16 + ec;
          Aout[(size_t)row * N + col] = f2bf(vv);
        }
      }
    }
  }
}

// sigmoid + scatter to original sample slots
__global__ void final_kernel(const float* __restrict__ z, const int* __restrict__ order,
                             const int* __restrict__ meta, float* __restrict__ out) {
  const int r = blockIdx.x * 256 + threadIdx.x;
  if (r < meta[1]) out[order[r]] = 1.f / (1.f + expf(-z[r]));
}

// -------- fallback GEMM (round-1): gating fused in staging, fp32 weights --------
template <int K, int N, bool GATHER>
__global__ void gemm_layer(const float* __restrict__ Xf, const short* __restrict__ Ain,
                           const float* __restrict__ w0, const float* __restrict__ wc,
                           short* __restrict__ Aout,
                           const int* __restrict__ order,
                           const int* __restrict__ tile_c, const int* __restrict__ tile_r,
                           const int* __restrict__ meta) {
  const int bt = blockIdx.x;
  if (bt >= meta[0]) return;
  const int cl = tile_c[bt];
  const int row0 = tile_r[bt];
  const int n0 = blockIdx.y * 128;

  __shared__ __align__(16) short As[128 * 40];
  __shared__ __align__(16) short Bs[128 * 40];

  const int tid = threadIdx.x;
  const int lane = tid & 63;
  const int wm = (tid >> 6) >> 1;
  const int wn = (tid >> 6) & 1;

  f32x4 acc[4][4] = {};

  const int arow = tid >> 2;
  const int akseg = (tid & 3) << 3;
  const int bn = tid & 127;
  const int bkq = (tid >> 7) << 3;

  const float* xr0 = nullptr; const float* xr1 = nullptr;
  const short* ar0 = nullptr; const short* ar1 = nullptr;
  if (GATHER) {
    xr0 = Xf + (size_t)order[row0 + arow] * K + akseg;
    xr1 = Xf + (size_t)order[row0 + arow + 64] * K + akseg;
  } else {
    ar0 = Ain + (size_t)(row0 + arow) * K + akseg;
    ar1 = Ain + (size_t)(row0 + arow + 64) * K + akseg;
  }
  const float* w0p = w0 + n0 + bn;
  const float* wcp = wc + (size_t)cl * K * N + n0 + bn;

  for (int kb = 0; kb < K; kb += 32) {
    __syncthreads();
    if (GATHER) {
      float4 a = *(const float4*)(xr0 + kb);
      float4 b = *(const float4*)(xr0 + kb + 4);
      short8 v;
      v[0] = f2bf(a.x); v[1] = f2bf(a.y); v[2] = f2bf(a.z); v[3] = f2bf(a.w);
      v[4] = f2bf(b.x); v[5] = f2bf(b.y); v[6] = f2bf(b.z); v[7] = f2bf(b.w);
      *(short8*)&As[arow * 40 + akseg] = v;
      a = *(const float4*)(xr1 + kb);
      b = *(const float4*)(xr1 + kb + 4);
      v[0] = f2bf(a.x); v[1] = f2bf(a.y); v[2] = f2bf(a.z); v[3] = f2bf(a.w);
      v[4] = f2bf(b.x); v[5] = f2bf(b.y); v[6] = f2bf(b.z); v[7] = f2bf(b.w);
      *(short8*)&As[(arow + 64) * 40 + akseg] = v;
    } else {
      *(short8*)&As[arow * 40 + akseg] = *(const short8*)(ar0 + kb);
      *(short8*)&As[(arow + 64) * 40 + akseg] = *(const short8*)(ar1 + kb);
    }
#pragma unroll
    for (int half = 0; half < 2; ++half) {
      const int kk = bkq + half * 16;
      short8 v;
#pragma unroll
      for (int j = 0; j < 8; ++j) {
        const size_t off = (size_t)(kb + kk + j) * N;
        v[j] = f2bf(w0p[off] * wcp[off]);
      }
      *(short8*)&Bs[bn * 40 + kk] = v;
    }
    __syncthreads();

    const int arL = wm * 64 + (lane & 15);
    const int kq = (lane >> 4) << 3;
    const int bcL = wn * 64 + (lane & 15);
    short8 af[4], bfr[4];
#pragma unroll
    for (int mi = 0; mi < 4; ++mi) af[mi] = *(const short8*)&As[(arL + mi * 16) * 40 + kq];
#pragma unroll
    for (int ni = 0; ni < 4; ++ni) bfr[ni] = *(const short8*)&Bs[(bcL + ni * 16) * 40 + kq];
#pragma unroll
    for (int mi = 0; mi < 4; ++mi) {
#pragma unroll
      for (int ni = 0; ni < 4; ++ni) {
        acc[mi][ni] = __builtin_amdgcn_mfma_f32_16x16x32_bf16(
            __builtin_bit_cast(bf16x8, af[mi]), __builtin_bit_cast(bf16x8, bfr[ni]),
            acc[mi][ni], 0, 0, 0);
      }
    }
  }

  const int er = (lane >> 4) << 2;
  const int ec = lane & 15;
#pragma unroll
  for (int mi = 0; mi < 4; ++mi) {
#pragma unroll
    for (int ni = 0; ni < 4; ++ni) {
#pragma unroll
      for (int r = 0; r < 4; ++r) {
        float vv = fmaxf(acc[mi][ni][r], 0.f);
        const int row = row0 + wm * 64 + mi * 16 + er + r;
        const int col = n0 + wn * 64 + ni * 16 + ec;
        Aout[(size_t)row * N + col] = f2bf(vv);
      }
    }
  }
}

// fallback final layer (reads h2 bf16)
__global__ void layer3_kernel(const short* __restrict__ h2, const float* __restrict__ w03,
                              const float* __restrict__ wc3, const int* __restrict__ order,
                              const int* __restrict__ pstart, const int* __restrict__ meta,
                              float* __restrict__ out) {
  const int tid = threadIdx.x;
  const int lane = tid & 63;
  const int w = tid >> 6;
  const int r = blockIdx.x * 4 + w;
  if (r >= meta[1]) return;
  int c = 0;
#pragma unroll
  for (int i = 1; i < CLN; ++i) { if (r >= pstart[i]) c = i; }
  const short* hr = h2 + (size_t)r * 512;
  const int k0 = lane * 8;
  const short8 hv = *(const short8*)(hr + k0);
  const float* wcr = wc3 + c * 512;
  float part = 0.f;
#pragma unroll
  for (int j = 0; j < 8; ++j) part += bf2f(hv[j]) * w03[k0 + j] * wcr[k0 + j];
  for (int off = 32; off; off >>= 1) part += __shfl_down(part, off);
  if (lane == 0) out[order[r]] = 1.f / (1.f + expf(-part));
}

extern "C" void kernel_launch(void* const* d_in, const int* in_sizes, int n_in,
                              void* d_out, int out_size, void* d_ws, size_t ws_size,
                              hipStream_t stream) {
  const float* x = (const float*)d_in[0];
  const float* center = (const float*)d_in[1];
  const float* w0s[4]; const float* wcs[4];
  if (in_sizes[3] == 8 * in_sizes[2]) {  // dict order: w0_i, wc_i interleaved
    for (int i = 0; i < 4; ++i) { w0s[i] = (const float*)d_in[2 + 2 * i]; wcs[i] = (const float*)d_in[3 + 2 * i]; }
  } else {                               // signature order: w0_0..w0_3, wc_0..wc_3
    for (int i = 0; i < 4; ++i) { w0s[i] = (const float*)d_in[2 + i]; wcs[i] = (const float*)d_in[6 + i]; }
  }
  float* out = (float*)d_out;
  char* ws = (char*)d_ws;
  int* counts = (int*)(ws + 0);      // 8
  int* pstart = (int*)(ws + 128);    // 9
  int* meta   = (int*)(ws + 192);    // 2
  int* tile_c = (int*)(ws + 256);    // 72
  int* tile_r = (int*)(ws + 1024);   // 72
  int* router = (int*)(ws + 4096);   // 8192 ints
  int* order  = (int*)(ws + 4096 + 4 * B_SZ);         // 9216 ints
  float* z    = (float*)(ws + 4096 + 4 * B_SZ + 4 * PADMAX);  // 9216 floats, ends < 131072

  const size_t GW0 = (size_t)CLN * 1024 * 2048 * 2;   // 33.55 MB
  const size_t GW1 = (size_t)CLN * 2048 * 1024 * 2;   // 33.55 MB
  const size_t GW2 = (size_t)CLN * 1024 * 512 * 2;    // 8.39 MB
  const size_t H0B = (size_t)PADMAX * 2048 * 2;       // 37.75 MB
  const size_t H1B = (size_t)PADMAX * 1024 * 2;       // 18.87 MB (>= xb 16.8 MB)
  const size_t NEED_A = 131072 + GW0 + GW1 + GW2 + H0B + H1B;  // ~132 MB (proven fits)
  const size_t NEED_B = 131072 + GW1 + H0B + H1B;              // ~90 MB
  const int tier = (ws_size >= NEED_A) ? 0 : (ws_size >= NEED_B) ? 1 : 2;

  if (tier == 0) {
    short* gw0 = (short*)(ws + 131072);
    short* gw1 = (short*)(ws + 131072 + GW0);
    short* gw2 = (short*)(ws + 131072 + GW0 + GW1);
    short* h0  = (short*)(ws + 131072 + GW0 + GW1 + GW2);
    short* h1  = (short*)(ws + 131072 + GW0 + GW1 + GW2 + H0B);
    short* xb  = h1;   // xb lives prep->gemm0; h1 lives gemm1->gemm2 (disjoint)

    prep_kernel<<<2048 + 9216, 256, 0, stream>>>(x, center, router, xb,
                                                 w0s[0], wcs[0], gw0,
                                                 w0s[1], wcs[1], gw1,
                                                 w0s[2], wcs[2], gw2);
    sort_kernel<<<1, 1024, 0, stream>>>(router, counts, pstart, meta, tile_c, tile_r, order, z);
    gemm_async<1024, 2048, true, false><<<MAX_TILES * 16, 256, 0, stream>>>(
        xb, gw0, h0, order, tile_c, tile_r, meta, nullptr, nullptr, nullptr);
    gemm_async<2048, 1024, false, false><<<MAX_TILES * 8, 256, 0, stream>>>(
        h0, gw1, h1, order, tile_c, tile_r, meta, nullptr, nullptr, nullptr);
    gemm_async<1024, 512, false, true><<<MAX_TILES * 4, 256, 0, stream>>>(
        h1, gw2, nullptr, order, tile_c, tile_r, meta, w0s[3], wcs[3], z);
    final_kernel<<<PADMAX / 256, 256, 0, stream>>>(z, order, meta, out);
  } else if (tier == 1) {
    short* gw = (short*)(ws + 131072);
    short* h0 = (short*)(ws + 131072 + GW1);
    short* h1 = (short*)(ws + 131072 + GW1 + H0B);
    short* xb = h1;

    prep_kernel<<<2048, 256, 0, stream>>>(x, center, router, xb,
                                          nullptr, nullptr, nullptr, nullptr, nullptr,
                                          nullptr, nullptr, nullptr, nullptr);
    sort_kernel<<<1, 1024, 0, stream>>>(router, counts, pstart, meta, tile_c, tile_r, order, z);
    gate1_kernel<1024, 2048><<<4096, 256, 0, stream>>>(w0s[0], wcs[0], gw);
    gemm_async<1024, 2048, true, false><<<MAX_TILES * 16, 256, 0, stream>>>(
        xb, gw, h0, order, tile_c, tile_r, meta, nullptr, nullptr, nullptr);
    gate1_kernel<2048, 1024><<<4096, 256, 0, stream>>>(w0s[1], wcs[1], gw);
    gemm_async<2048, 1024, false, false><<<MAX_TILES * 8, 256, 0, stream>>>(
        h0, gw, h1, order, tile_c, tile_r, meta, nullptr, nullptr, nullptr);
    gate1_kernel<1024, 512><<<1024, 256, 0, stream>>>(w0s[2], wcs[2], gw);
    gemm_async<1024, 512, false, true><<<MAX_TILES * 4, 256, 0, stream>>>(
        h1, gw, nullptr, order, tile_c, tile_r, meta, w0s[3], wcs[3], z);
    final_kernel<<<PADMAX / 256, 256, 0, stream>>>(z, order, meta, out);
  } else {
    short* f0 = (short*)(ws + 131072);
    short* f1 = f0 + (size_t)PADMAX * 2048;
    short* f2 = f1 + (size_t)PADMAX * 1024;
    prep_kernel<<<2048, 256, 0, stream>>>(x, center, router, nullptr,
                                          nullptr, nullptr, nullptr, nullptr, nullptr,
                                          nullptr, nullptr, nullptr, nullptr);
    sort_kernel<<<1, 1024, 0, stream>>>(router, counts, pstart, meta, tile_c, tile_r, order, z);
    gemm_layer<1024, 2048, true><<<dim3(MAX_TILES, 16), 256, 0, stream>>>(
        x, nullptr, w0s[0], wcs[0], f0, order, tile_c, tile_r, meta);
    gemm_layer<2048, 1024, false><<<dim3(MAX_TILES, 8), 256, 0, stream>>>(
        nullptr, f0, w0s[1], wcs[1], f1, order, tile_c, tile_r, meta);
    gemm_layer<1024, 512, false><<<dim3(MAX_TILES, 4), 256, 0, stream>>>(
        nullptr, f1, w0s[2], wcs[2], f2, order, tile_c, tile_r, meta);
    layer3_kernel<<<(PADMAX + 3) / 4, 256, 0, stream>>>(f2, w0s[3], wcs[3], order, pstart, meta, out);
  }
}